// Round 8
// baseline (193.432 us; speedup 1.0000x reference)
//
#include <hip/hip_runtime.h>
#include <hip/hip_bf16.h>

#define B_ 2
#define N_ 1024
#define D_ 64
#define L_ 3072
#define H_ 4

typedef __attribute__((ext_vector_type(8))) short s8v;
typedef __attribute__((ext_vector_type(4))) short s4v;
typedef __attribute__((ext_vector_type(4))) float f32x4;

#define EXP2F(x) __builtin_amdgcn_exp2f(x)
#define QSCALE 0.36067376022224085f   // 0.25 * log2(e)

__device__ __forceinline__ float wave_sum64(float v) {
#pragma unroll
    for (int off = 32; off > 0; off >>= 1) v += __shfl_xor(v, off, 64);
    return v;
}

// float -> bf16 bits, round-to-nearest-even (finite inputs only)
__device__ __forceinline__ short f2bf(float f) {
    unsigned u = __float_as_uint(f);
    u += 0x7FFFu + ((u >> 16) & 1u);
    return (short)(u >> 16);
}
// pack 2 floats -> 2 bf16 in one u32 (lo=a, hi=b), single VALU op
__device__ __forceinline__ unsigned cvt_pk_bf16(float a, float b) {
    unsigned r;
    asm("v_cvt_pk_bf16_f32 %0, %1, %2" : "=v"(r) : "v"(a), "v"(b));
    return r;
}
union pk8 { s8v v; unsigned u[4]; };
union pk4 { s4v v; unsigned u[2]; };

// MFMA fragment contract (HW-verified R4-R7):
//   frag F(Mat): F[lane(hi,lo)][s] = Mat[lo][kmap(hi,s)], kmap = 4hi+s (s<4), 16+4hi+s-4 (s>=4)
//   mfma(F(X), F(Y))[lane(hi,lo)][j] = sum_k X[4hi+j][k] * Y[lo][k]
__device__ __forceinline__ s8v ldfrag_pad(const __hip_bfloat16* p) {
    s4v lo4 = *reinterpret_cast<const s4v*>(p);
    s8v r;
    r[0] = lo4[0]; r[1] = lo4[1]; r[2] = lo4[2]; r[3] = lo4[3];
    r[4] = 0; r[5] = 0; r[6] = 0; r[7] = 0;
    return r;
}
__device__ __forceinline__ s8v ldfrag_full(const __hip_bfloat16* p0, const __hip_bfloat16* p1) {
    s4v a = *reinterpret_cast<const s4v*>(p0);
    s4v b = *reinterpret_cast<const s4v*>(p1);
    s8v r;
    r[0] = a[0]; r[1] = a[1]; r[2] = a[2]; r[3] = a[3];
    r[4] = b[0]; r[5] = b[1]; r[6] = b[2]; r[7] = b[3];
    return r;
}
// W-fragment for C = A @ W: F(W^T tile ct, k-step ks), fp32 W scaled+rounded to bf16
__device__ __forceinline__ s8v wfrag_build(const float* __restrict__ W, int N, int ct, int ks,
                                           int lo, int hi, float scale) {
    s8v r;
    int n = ct * 16 + lo;
    int k0 = ks * 32 + 4 * hi;
#pragma unroll
    for (int j = 0; j < 4; ++j) {
        r[j]     = f2bf(W[(k0 + j) * N + n] * scale);
        r[4 + j] = f2bf(W[(k0 + 16 + j) * N + n] * scale);
    }
    return r;
}

// ---------------------------------------------------------------------------
// K0: transpose x (fp32 [N,64]) -> xt (bf16 [64,N]) for q and v, per batch.
// ---------------------------------------------------------------------------
__global__ void xpose(const float* __restrict__ xq, const float* __restrict__ xv,
                      __hip_bfloat16* __restrict__ xtq, __hip_bfloat16* __restrict__ xtv) {
    __shared__ short ts[64][65];
    int m = blockIdx.y;
    int qv = m >> 1, b = m & 1;
    int l0 = blockIdx.x * 64;
    const float* x = (qv ? xv : xq) + (size_t)b * N_ * 64;
    int t = threadIdx.x;
#pragma unroll
    for (int i = 0; i < 4; ++i) {
        int f = t + i * 256;            // float4 idx 0..1023
        int r = f >> 4, c4 = f & 15;
        float4 v = *reinterpret_cast<const float4*>(x + (size_t)(l0 + r) * 64 + c4 * 4);
        ts[c4 * 4 + 0][r] = f2bf(v.x);
        ts[c4 * 4 + 1][r] = f2bf(v.y);
        ts[c4 * 4 + 2][r] = f2bf(v.z);
        ts[c4 * 4 + 3][r] = f2bf(v.w);
    }
    __syncthreads();
    short* xt = reinterpret_cast<short*>(qv ? xtv : xtq) + (size_t)b * 64 * N_;
#pragma unroll
    for (int i = 0; i < 4; ++i) {
        int f = t + i * 256;
        int d = f >> 4, seg = f & 15;
        s4v o;
        o[0] = ts[d][seg * 4 + 0]; o[1] = ts[d][seg * 4 + 1];
        o[2] = ts[d][seg * 4 + 2]; o[3] = ts[d][seg * 4 + 3];
        *reinterpret_cast<s4v*>(xt + (size_t)d * N_ + l0 + seg * 4) = o;
    }
}

// ---------------------------------------------------------------------------
// K1: one diffusion hop via MFMA: C = adj @ X, per (b, q/v).
// 8 waves: 4 col-tiles x 2 k-halves; LDS merge. grid (64,2,2) x 512.
// ---------------------------------------------------------------------------
__global__ __launch_bounds__(512) void spmm_mfma(
        const float* __restrict__ adj_q, const float* __restrict__ adj_v,
        const __hip_bfloat16* __restrict__ xtq, const __hip_bfloat16* __restrict__ xtv,
        float* __restrict__ oq, float* __restrict__ ov,
        __hip_bfloat16* __restrict__ oqt, __hip_bfloat16* __restrict__ ovt, int writet) {
    const int lane = threadIdx.x & 63;
    const int w = threadIdx.x >> 6;          // 0..7
    const int ct = w & 3, kh = w >> 2;       // col-tile, k-half
    const int lo = lane & 15, hi = lane >> 4;
    const int rt = blockIdx.x;               // row-tile 0..63
    const int qv = blockIdx.y, b = blockIdx.z;

    const float* adj = (qv ? adj_v : adj_q) + (size_t)b * N_ * N_ + (size_t)(rt * 16 + lo) * N_;
    const __hip_bfloat16* xt = (qv ? xtv : xtq) + ((size_t)b * 64 + ct * 16 + lo) * N_;

    f32x4 acc = {0.f, 0.f, 0.f, 0.f};
#pragma unroll 4
    for (int ks = kh * 16; ks < kh * 16 + 16; ++ks) {
        int k0 = ks * 32;
        float4 a4 = *reinterpret_cast<const float4*>(adj + k0 + 4 * hi);
        float4 b4 = *reinterpret_cast<const float4*>(adj + k0 + 16 + 4 * hi);
        pk8 af;
        af.u[0] = cvt_pk_bf16(a4.x, a4.y); af.u[1] = cvt_pk_bf16(a4.z, a4.w);
        af.u[2] = cvt_pk_bf16(b4.x, b4.y); af.u[3] = cvt_pk_bf16(b4.z, b4.w);
        s8v xf = ldfrag_full(xt + k0 + 4 * hi, xt + k0 + 16 + 4 * hi);
        acc = __builtin_amdgcn_mfma_f32_16x16x32_bf16(xf, af.v, acc, 0, 0, 0);
    }
    __shared__ float red[2][4][64][4];
    red[kh][ct][lane][0] = acc[0]; red[kh][ct][lane][1] = acc[1];
    red[kh][ct][lane][2] = acc[2]; red[kh][ct][lane][3] = acc[3];
    __syncthreads();
    if (kh == 0) {
        f32x4 s;
#pragma unroll
        for (int j = 0; j < 4; ++j) s[j] = red[0][ct][lane][j] + red[1][ct][lane][j];
        float* o = (qv ? ov : oq) + ((size_t)b * N_ + rt * 16 + lo) * 64 + ct * 16 + 4 * hi;
        *reinterpret_cast<f32x4*>(o) = s;
        if (writet) {
            short* ot = reinterpret_cast<short*>(qv ? ovt : oqt) + (size_t)b * 64 * N_;
#pragma unroll
            for (int j = 0; j < 4; ++j)
                ot[(size_t)(ct * 16 + 4 * hi + j) * N_ + rt * 16 + lo] = f2bf(s[j]);
        }
    }
}

// ---------------------------------------------------------------------------
// K2: concat along node axis + LayerNorm(eps=1e-5, no affine).
// ---------------------------------------------------------------------------
__global__ void concat_ln(const float* __restrict__ qx, const float* __restrict__ q1,
                          const float* __restrict__ q2,
                          const float* __restrict__ vx, const float* __restrict__ v1,
                          const float* __restrict__ v2,
                          float* __restrict__ qc,
                          __hip_bfloat16* __restrict__ qcb, __hip_bfloat16* __restrict__ vcb) {
    int rid  = blockIdx.x * 4 + (threadIdx.x >> 6);
    int lane = threadIdx.x & 63;
    int qvsel = rid >= (B_ * L_);
    int r = qvsel ? rid - B_ * L_ : rid;
    int b = r / L_, l = r % L_;
    int s = l / N_, i = l % N_;
    const float* src;
    if (!qvsel) src = (s == 0) ? qx : (s == 1) ? q1 : q2;
    else        src = (s == 0) ? vx : (s == 1) ? v1 : v2;
    float v = src[((size_t)b * N_ + i) * D_ + lane];
    float mean = wave_sum64(v) * (1.0f / 64.0f);
    float d = v - mean;
    float var = wave_sum64(d * d) * (1.0f / 64.0f);
    float y = d * rsqrtf(var + 1e-5f);
    size_t o = ((size_t)b * L_ + l) * D_ + lane;
    if (!qvsel) {
        qc[o] = y;
        reinterpret_cast<short*>(qcb)[o] = f2bf(y);
    } else {
        reinterpret_cast<short*>(vcb)[o] = f2bf(y);
    }
}

// ---------------------------------------------------------------------------
// K3: fused qkv projection, MFMA. 12 col-tiles: [wq:4 | wk:4 | wv:4].
// ---------------------------------------------------------------------------
__global__ __launch_bounds__(256) void gemm_qkv(
        const __hip_bfloat16* __restrict__ qcb, const __hip_bfloat16* __restrict__ vcb,
        const float* __restrict__ wq, const float* __restrict__ wk, const float* __restrict__ wv,
        __hip_bfloat16* __restrict__ qb, __hip_bfloat16* __restrict__ kb,
        __hip_bfloat16* __restrict__ vtb) {
    const int w = threadIdx.x >> 6;
    const int lane = threadIdx.x & 63;
    const int lo = lane & 15, hi = lane >> 4;
    const int ct0 = w * 3;

    s8v wf[3][2];
#pragma unroll
    for (int c = 0; c < 3; ++c) {
        int ct = ct0 + c;
        const float* W = (ct < 4) ? wq : (ct < 8) ? wk : wv;
        float sc = (ct < 4) ? QSCALE : 1.0f;
        wf[c][0] = wfrag_build(W, 64, ct & 3, 0, lo, hi, sc);
        wf[c][1] = wfrag_build(W, 64, ct & 3, 1, lo, hi, sc);
    }
    const bool needq = (ct0 < 8);
    const bool needv = (ct0 + 2 >= 8);
    const f32x4 zz = {0.f, 0.f, 0.f, 0.f};

#pragma unroll
    for (int rr = 0; rr < 2; ++rr) {
        int rt = blockIdx.x * 2 + rr;
        int rbase = rt * 16;
        int b = rbase / L_;
        int l = rbase % L_ + lo;
        s8v aq0, aq1, av0, av1;
        if (needq) {
            const __hip_bfloat16* ar = qcb + (size_t)(rbase + lo) * 64;
            aq0 = ldfrag_full(ar + 4 * hi, ar + 16 + 4 * hi);
            aq1 = ldfrag_full(ar + 32 + 4 * hi, ar + 48 + 4 * hi);
        }
        if (needv) {
            const __hip_bfloat16* ar = vcb + (size_t)(rbase + lo) * 64;
            av0 = ldfrag_full(ar + 4 * hi, ar + 16 + 4 * hi);
            av1 = ldfrag_full(ar + 32 + 4 * hi, ar + 48 + 4 * hi);
        }
#pragma unroll
        for (int c = 0; c < 3; ++c) {
            int ct = ct0 + c;
            f32x4 acc = zz;
            if (ct < 8) {
                acc = __builtin_amdgcn_mfma_f32_16x16x32_bf16(wf[c][0], aq0, acc, 0, 0, 0);
                acc = __builtin_amdgcn_mfma_f32_16x16x32_bf16(wf[c][1], aq1, acc, 0, 0, 0);
                __hip_bfloat16* dst = (ct < 4) ? qb : kb;
                int h = ct & 3;
                pk4 o;
                o.u[0] = cvt_pk_bf16(acc[0], acc[1]);
                o.u[1] = cvt_pk_bf16(acc[2], acc[3]);
                *reinterpret_cast<s4v*>(reinterpret_cast<short*>(dst) +
                    ((size_t)(b * H_ + h) * L_ + l) * 16 + 4 * hi) = o.v;
            } else {
                acc = __builtin_amdgcn_mfma_f32_16x16x32_bf16(wf[c][0], av0, acc, 0, 0, 0);
                acc = __builtin_amdgcn_mfma_f32_16x16x32_bf16(wf[c][1], av1, acc, 0, 0, 0);
                int h = ct - 8;
                short* vt = reinterpret_cast<short*>(vtb);
#pragma unroll
                for (int j = 0; j < 4; ++j) {
                    int dv = 4 * hi + j;
                    vt[((size_t)(b * H_ + h) * 16 + dv) * L_ + l] = f2bf(acc[j]);
                }
            }
        }
    }
}

// ---------------------------------------------------------------------------
// K4: MFMA flash attention, fixed-max softmax. 8 waves = 4 key-groups x 2
// q-tiles; register-prefetched K/V fragments; cvt_pk P-pack; pure-sum LDS
// merge. grid 768 x 512. Output bf16.
// ---------------------------------------------------------------------------
__global__ __launch_bounds__(512) void attn_mfma(
        const __hip_bfloat16* __restrict__ qb, const __hip_bfloat16* __restrict__ kb,
        const __hip_bfloat16* __restrict__ vtb, __hip_bfloat16* __restrict__ attnob) {
    const int lane = threadIdx.x & 63;
    const int w = threadIdx.x >> 6;          // 0..7
    const int qt2 = w & 1, kg = w >> 1;      // q-tile, key-group
    const int g = blockIdx.x;                // 0..767
    const int bh = g / 96;                   // L/32 = 96 q-pairs per (b,h)
    const int tp = g % 96;
    const int b = bh >> 2, h = bh & 3;
    const int lo = lane & 15, hi = lane >> 4;
    const int q0 = tp * 32 + qt2 * 16;

    const __hip_bfloat16* qbase = qb + (size_t)bh * L_ * 16;
    const __hip_bfloat16* kbase = kb + (size_t)bh * L_ * 16;
    const __hip_bfloat16* vtbase = vtb + ((size_t)bh * 16 + lo) * L_;  // row = dv = lo

    s8v qf = ldfrag_pad(qbase + (size_t)(q0 + lo) * 16 + 4 * hi);

    f32x4 acc = {0.f, 0.f, 0.f, 0.f};
    float ls = 0.f;
    const f32x4 zz = {0.f, 0.f, 0.f, 0.f};

    const int kbeg = kg * (L_ / 4), kend = kbeg + (L_ / 4);   // 768 keys, 24 iters
    // prefetch first tile
    s8v kf0 = ldfrag_pad(kbase + (size_t)(kbeg + lo) * 16 + 4 * hi);
    s8v kf1 = ldfrag_pad(kbase + (size_t)(kbeg + 16 + lo) * 16 + 4 * hi);
    s8v vf  = ldfrag_full(vtbase + kbeg + 4 * hi, vtbase + kbeg + 16 + 4 * hi);

    for (int kt = kbeg; kt < kend; kt += 32) {
        s8v ck0 = kf0, ck1 = kf1, cv = vf;
        int nk = (kt + 32 < kend) ? kt + 32 : kbeg;
        kf0 = ldfrag_pad(kbase + (size_t)(nk + lo) * 16 + 4 * hi);
        kf1 = ldfrag_pad(kbase + (size_t)(nk + 16 + lo) * 16 + 4 * hi);
        vf  = ldfrag_full(vtbase + nk + 4 * hi, vtbase + nk + 16 + 4 * hi);

        f32x4 s0 = __builtin_amdgcn_mfma_f32_16x16x32_bf16(ck0, qf, zz, 0, 0, 0);
        f32x4 s1 = __builtin_amdgcn_mfma_f32_16x16x32_bf16(ck1, qf, zz, 0, 0, 0);

        float p0 = EXP2F(s0[0]), p1 = EXP2F(s0[1]), p2 = EXP2F(s0[2]), p3 = EXP2F(s0[3]);
        float p4 = EXP2F(s1[0]), p5 = EXP2F(s1[1]), p6 = EXP2F(s1[2]), p7 = EXP2F(s1[3]);
        ls += ((p0 + p1) + (p2 + p3)) + ((p4 + p5) + (p6 + p7));

        pk8 pf;
        pf.u[0] = cvt_pk_bf16(p0, p1); pf.u[1] = cvt_pk_bf16(p2, p3);
        pf.u[2] = cvt_pk_bf16(p4, p5); pf.u[3] = cvt_pk_bf16(p6, p7);

        acc = __builtin_amdgcn_mfma_f32_16x16x32_bf16(cv, pf.v, acc, 0, 0, 0);
    }

    ls += __shfl_xor(ls, 16, 64);
    ls += __shfl_xor(ls, 32, 64);

    __shared__ float red[4][2][64][5];
    red[kg][qt2][lane][0] = acc[0]; red[kg][qt2][lane][1] = acc[1];
    red[kg][qt2][lane][2] = acc[2]; red[kg][qt2][lane][3] = acc[3];
    red[kg][qt2][lane][4] = ls;
    __syncthreads();
    if (w < 2) {
        int t = w;   // q-tile
        float a0 = 0.f, a1 = 0.f, a2 = 0.f, a3 = 0.f, lt = 0.f;
#pragma unroll
        for (int g2 = 0; g2 < 4; ++g2) {
            a0 += red[g2][t][lane][0];
            a1 += red[g2][t][lane][1];
            a2 += red[g2][t][lane][2];
            a3 += red[g2][t][lane][3];
            lt += red[g2][t][lane][4];
        }
        float inv = 1.0f / lt;
        pk4 o;
        o.u[0] = cvt_pk_bf16(a0 * inv, a1 * inv);
        o.u[1] = cvt_pk_bf16(a2 * inv, a3 * inv);
        *reinterpret_cast<s4v*>(reinterpret_cast<short*>(attnob) +
            ((size_t)b * L_ + tp * 32 + t * 16 + lo) * 64 + h * 16 + 4 * hi) = o.v;
    }
}

// ---------------------------------------------------------------------------
// K5: o2 = LN( attnob @ w_fc + qc ; mha_ln, eps 1e-6 ), MFMA. grid 96 x 256.
// ---------------------------------------------------------------------------
__global__ __launch_bounds__(256) void gemm_fc_ln(
        const __hip_bfloat16* __restrict__ attnob, const float* __restrict__ qc,
        const float* __restrict__ wfc,
        const float* __restrict__ lnw, const float* __restrict__ lnb,
        float* __restrict__ o2) {
    const int rt = blockIdx.x * 4 + (threadIdx.x >> 6);   // 0..383
    const int lane = threadIdx.x & 63;
    const int lo = lane & 15, hi = lane >> 4;
    const f32x4 zz = {0.f, 0.f, 0.f, 0.f};

    s8v wf[4][2];
#pragma unroll
    for (int ct = 0; ct < 4; ++ct) {
        wf[ct][0] = wfrag_build(wfc, 64, ct, 0, lo, hi, 1.0f);
        wf[ct][1] = wfrag_build(wfc, 64, ct, 1, lo, hi, 1.0f);
    }
    const __hip_bfloat16* ar = attnob + (size_t)(rt * 16 + lo) * 64;
    s8v a0 = ldfrag_full(ar + 4 * hi, ar + 16 + 4 * hi);
    s8v a1 = ldfrag_full(ar + 32 + 4 * hi, ar + 48 + 4 * hi);

    f32x4 acc[4];
    const int row = rt * 16 + lo;
#pragma unroll
    for (int ct = 0; ct < 4; ++ct) {
        acc[ct] = zz;
        acc[ct] = __builtin_amdgcn_mfma_f32_16x16x32_bf16(wf[ct][0], a0, acc[ct], 0, 0, 0);
        acc[ct] = __builtin_amdgcn_mfma_f32_16x16x32_bf16(wf[ct][1], a1, acc[ct], 0, 0, 0);
        f32x4 rq = *reinterpret_cast<const f32x4*>(qc + (size_t)row * 64 + ct * 16 + 4 * hi);
        acc[ct][0] += rq[0]; acc[ct][1] += rq[1]; acc[ct][2] += rq[2]; acc[ct][3] += rq[3];
    }
    float s = 0.f;
#pragma unroll
    for (int ct = 0; ct < 4; ++ct) s += (acc[ct][0] + acc[ct][1]) + (acc[ct][2] + acc[ct][3]);
    s += __shfl_xor(s, 16, 64); s += __shfl_xor(s, 32, 64);
    float mean = s * (1.0f / 64.0f);
    float vs = 0.f;
#pragma unroll
    for (int ct = 0; ct < 4; ++ct) {
#pragma unroll
        for (int j = 0; j < 4; ++j) { float d = acc[ct][j] - mean; vs += d * d; }
    }
    vs += __shfl_xor(vs, 16, 64); vs += __shfl_xor(vs, 32, 64);
    float rsq = rsqrtf(vs * (1.0f / 64.0f) + 1e-6f);
#pragma unroll
    for (int ct = 0; ct < 4; ++ct) {
        f32x4 w4 = *reinterpret_cast<const f32x4*>(lnw + ct * 16 + 4 * hi);
        f32x4 b4 = *reinterpret_cast<const f32x4*>(lnb + ct * 16 + 4 * hi);
        f32x4 o;
#pragma unroll
        for (int j = 0; j < 4; ++j) o[j] = (acc[ct][j] - mean) * rsq * w4[j] + b4[j];
        *reinterpret_cast<f32x4*>(o2 + (size_t)row * 64 + ct * 16 + 4 * hi) = o;
    }
}

// ---------------------------------------------------------------------------
// K6: pool: x[b,i,j] = mean_s o2flat[b, 192 i + 3 j + s] -> xb bf16 [2048,64].
// ---------------------------------------------------------------------------
__global__ void pool_k(const float* __restrict__ o2, __hip_bfloat16* __restrict__ xb) {
    int rid  = blockIdx.x * 4 + (threadIdx.x >> 6);  // b*N + i
    int lane = threadIdx.x & 63;
    int b = rid / N_, i = rid % N_;
    const float* ob = o2 + (size_t)b * L_ * 64 + (size_t)192 * i;
    int t = 3 * lane;
    float xv = (ob[t] + ob[t + 1] + ob[t + 2]) * (1.0f / 3.0f);
    reinterpret_cast<short*>(xb)[(size_t)rid * 64 + lane] = f2bf(xv);
}

// ---------------------------------------------------------------------------
// K7: x1 = relu( xb @ conv_w + conv_b ) -> bf16 [2048,128], MFMA. grid 128.
// ---------------------------------------------------------------------------
__global__ __launch_bounds__(256) void gemm_conv(
        const __hip_bfloat16* __restrict__ xb, const float* __restrict__ convw,
        const float* __restrict__ convb, __hip_bfloat16* __restrict__ x1b) {
    const int w = threadIdx.x >> 6;
    const int lane = threadIdx.x & 63;
    const int lo = lane & 15, hi = lane >> 4;
    const int rt = blockIdx.x;               // 0..127
    const f32x4 zz = {0.f, 0.f, 0.f, 0.f};

    s8v wf[2][2];
#pragma unroll
    for (int c = 0; c < 2; ++c) {
        int ct = 2 * w + c;
        wf[c][0] = wfrag_build(convw, 128, ct, 0, lo, hi, 1.0f);
        wf[c][1] = wfrag_build(convw, 128, ct, 1, lo, hi, 1.0f);
    }
    const __hip_bfloat16* ar = xb + (size_t)(rt * 16 + lo) * 64;
    s8v a0 = ldfrag_full(ar + 4 * hi, ar + 16 + 4 * hi);
    s8v a1 = ldfrag_full(ar + 32 + 4 * hi, ar + 48 + 4 * hi);

#pragma unroll
    for (int c = 0; c < 2; ++c) {
        int ct = 2 * w + c;
        f32x4 acc = zz;
        acc = __builtin_amdgcn_mfma_f32_16x16x32_bf16(wf[c][0], a0, acc, 0, 0, 0);
        acc = __builtin_amdgcn_mfma_f32_16x16x32_bf16(wf[c][1], a1, acc, 0, 0, 0);
        f32x4 bia = *reinterpret_cast<const f32x4*>(convb + ct * 16 + 4 * hi);
        pk4 o;
        o.u[0] = cvt_pk_bf16(fmaxf(acc[0] + bia[0], 0.f), fmaxf(acc[1] + bia[1], 0.f));
        o.u[1] = cvt_pk_bf16(fmaxf(acc[2] + bia[2], 0.f), fmaxf(acc[3] + bia[3], 0.f));
        *reinterpret_cast<s4v*>(reinterpret_cast<short*>(x1b) +
            (size_t)(rt * 16 + lo) * 128 + ct * 16 + 4 * hi) = o.v;
    }
}

// ---------------------------------------------------------------------------
// K8: out = LN( q_x + x1b @ lin_w + lin_b ; norm, eps 1e-5 ), MFMA, K=128.
// ---------------------------------------------------------------------------
__global__ __launch_bounds__(256) void gemm_lin_ln(
        const __hip_bfloat16* __restrict__ x1b, const float* __restrict__ qx,
        const float* __restrict__ linw, const float* __restrict__ linb,
        const float* __restrict__ nw, const float* __restrict__ nb,
        float* __restrict__ out) {
    const int rt = blockIdx.x * 4 + (threadIdx.x >> 6);   // 0..127
    const int lane = threadIdx.x & 63;
    const int lo = lane & 15, hi = lane >> 4;
    const f32x4 zz = {0.f, 0.f, 0.f, 0.f};

    s8v wf[4][4];
#pragma unroll
    for (int ct = 0; ct < 4; ++ct)
#pragma unroll
        for (int ks = 0; ks < 4; ++ks)
            wf[ct][ks] = wfrag_build(linw, 64, ct, ks, lo, hi, 1.0f);

    const __hip_bfloat16* ar = x1b + (size_t)(rt * 16 + lo) * 128;
    s8v af[4];
#pragma unroll
    for (int ks = 0; ks < 4; ++ks)
        af[ks] = ldfrag_full(ar + ks * 32 + 4 * hi, ar + ks * 32 + 16 + 4 * hi);

    f32x4 acc[4];
    const int row = rt * 16 + lo;
#pragma unroll
    for (int ct = 0; ct < 4; ++ct) {
        acc[ct] = zz;
#pragma unroll
        for (int ks = 0; ks < 4; ++ks)
            acc[ct] = __builtin_amdgcn_mfma_f32_16x16x32_bf16(wf[ct][ks], af[ks], acc[ct], 0, 0, 0);
        f32x4 bia = *reinterpret_cast<const f32x4*>(linb + ct * 16 + 4 * hi);
        f32x4 rq  = *reinterpret_cast<const f32x4*>(qx + (size_t)row * 64 + ct * 16 + 4 * hi);
#pragma unroll
        for (int j = 0; j < 4; ++j) acc[ct][j] += bia[j] + rq[j];
    }
    float s = 0.f;
#pragma unroll
    for (int ct = 0; ct < 4; ++ct) s += (acc[ct][0] + acc[ct][1]) + (acc[ct][2] + acc[ct][3]);
    s += __shfl_xor(s, 16, 64); s += __shfl_xor(s, 32, 64);
    float mean = s * (1.0f / 64.0f);
    float vs = 0.f;
#pragma unroll
    for (int ct = 0; ct < 4; ++ct) {
#pragma unroll
        for (int j = 0; j < 4; ++j) { float d = acc[ct][j] - mean; vs += d * d; }
    }
    vs += __shfl_xor(vs, 16, 64); vs += __shfl_xor(vs, 32, 64);
    float rsq = rsqrtf(vs * (1.0f / 64.0f) + 1e-5f);
#pragma unroll
    for (int ct = 0; ct < 4; ++ct) {
        f32x4 w4 = *reinterpret_cast<const f32x4*>(nw + ct * 16 + 4 * hi);
        f32x4 b4 = *reinterpret_cast<const f32x4*>(nb + ct * 16 + 4 * hi);
        f32x4 o;
#pragma unroll
        for (int j = 0; j < 4; ++j) o[j] = (acc[ct][j] - mean) * rsq * w4[j] + b4[j];
        *reinterpret_cast<f32x4*>(out + (size_t)row * 64 + ct * 16 + 4 * hi) = o;
    }
}

// ---------------------------------------------------------------------------
extern "C" void kernel_launch(void* const* d_in, const int* in_sizes, int n_in,
                              void* d_out, int out_size, void* d_ws, size_t ws_size,
                              hipStream_t stream) {
    const float* q_x      = (const float*)d_in[0];
    const float* q_adj    = (const float*)d_in[1];
    const float* v_x      = (const float*)d_in[2];
    const float* v_adj    = (const float*)d_in[3];
    const float* w_qs     = (const float*)d_in[4];
    const float* w_ks     = (const float*)d_in[5];
    const float* w_vs     = (const float*)d_in[6];
    const float* w_fc     = (const float*)d_in[7];
    const float* mha_ln_w = (const float*)d_in[8];
    const float* mha_ln_b = (const float*)d_in[9];
    const float* conv_w   = (const float*)d_in[10];
    const float* conv_b   = (const float*)d_in[11];
    const float* lin_w    = (const float*)d_in[12];
    const float* lin_b    = (const float*)d_in[13];
    const float* norm_w   = (const float*)d_in[14];
    const float* norm_b   = (const float*)d_in[15];

    float* ws = (float*)d_ws;
    float* q1    = ws;                 // 131072 f each
    float* v1    = q1 + 131072;
    float* q2    = v1 + 131072;
    float* v2    = q2 + 131072;
    float* qc    = v2 + 131072;        // 393216 f
    float* o2    = qc + 393216;        // 393216 f
    __hip_bfloat16* qcb    = (__hip_bfloat16*)(o2 + 393216);   // 393216 bf16 each
    __hip_bfloat16* vcb    = qcb + 393216;
    __hip_bfloat16* qb     = vcb + 393216;                     // [BH,L,16]
    __hip_bfloat16* kb     = qb + 393216;
    __hip_bfloat16* vtb    = kb + 393216;                      // [BH,16,L]
    __hip_bfloat16* attnob = vtb + 393216;                     // [B*L,64]
    __hip_bfloat16* xtq    = attnob + 393216;                  // [B,64,1024] bf16
    __hip_bfloat16* xtv    = xtq + 131072;
    __hip_bfloat16* q1t    = xtv + 131072;
    __hip_bfloat16* v1t    = q1t + 131072;
    __hip_bfloat16* xb     = v1t + 131072;                     // [2048,64]
    __hip_bfloat16* x1b    = xb + 131072;                      // [2048,128]
    float* out   = (float*)d_out;

    xpose<<<dim3(16, 4), 256, 0, stream>>>(q_x, v_x, xtq, xtv);
    spmm_mfma<<<dim3(64, 2, 2), 512, 0, stream>>>(q_adj, v_adj, xtq, xtv,
                                                  q1, v1, q1t, v1t, 1);
    spmm_mfma<<<dim3(64, 2, 2), 512, 0, stream>>>(q_adj, v_adj, q1t, v1t,
                                                  q2, v2, nullptr, nullptr, 0);
    concat_ln<<<3072, 256, 0, stream>>>(q_x, q1, q2, v_x, v1, v2, qc, qcb, vcb);
    gemm_qkv<<<192, 256, 0, stream>>>(qcb, vcb, w_qs, w_ks, w_vs, qb, kb, vtb);
    attn_mfma<<<768, 512, 0, stream>>>(qb, kb, vtb, attnob);
    gemm_fc_ln<<<96, 256, 0, stream>>>(attnob, qc, w_fc, mha_ln_w, mha_ln_b, o2);
    pool_k<<<512, 256, 0, stream>>>(o2, xb);
    gemm_conv<<<128, 256, 0, stream>>>(xb, conv_w, conv_b, x1b);
    gemm_lin_ln<<<32, 256, 0, stream>>>(x1b, q_x, lin_w, lin_b, norm_w, norm_b, out);
}

// Round 10
// 168.914 us; speedup vs baseline: 1.1451x; 1.1451x over previous
//
#include <hip/hip_runtime.h>
#include <hip/hip_bf16.h>

#define B_ 2
#define N_ 1024
#define D_ 64
#define L_ 3072
#define H_ 4

typedef __attribute__((ext_vector_type(8))) short s8v;
typedef __attribute__((ext_vector_type(4))) short s4v;
typedef __attribute__((ext_vector_type(4))) float f32x4;

#define EXP2F(x) __builtin_amdgcn_exp2f(x)
#define QSCALE 0.36067376022224085f   // 0.25 * log2(e)

__device__ __forceinline__ float wave_sum64(float v) {
#pragma unroll
    for (int off = 32; off > 0; off >>= 1) v += __shfl_xor(v, off, 64);
    return v;
}

// float -> bf16 bits, round-to-nearest-even (finite inputs only)
__device__ __forceinline__ short f2bf(float f) {
    unsigned u = __float_as_uint(f);
    u += 0x7FFFu + ((u >> 16) & 1u);
    return (short)(u >> 16);
}
// pack 2 floats -> 2 bf16 in one u32 (lo=a, hi=b), single VALU op
__device__ __forceinline__ unsigned cvt_pk_bf16(float a, float b) {
    unsigned r;
    asm("v_cvt_pk_bf16_f32 %0, %1, %2" : "=v"(r) : "v"(a), "v"(b));
    return r;
}
union pk8 { s8v v; unsigned u[4]; };
union pk4 { s4v v; unsigned u[2]; };

// MFMA fragment contract (HW-verified R4-R8):
//   frag F(Mat): F[lane(hi,lo)][s] = Mat[lo][kmap(hi,s)], kmap = 4hi+s (s<4), 16+4hi+s-4 (s>=4)
//   mfma(F(X), F(Y))[lane(hi,lo)][j] = sum_k X[4hi+j][k] * Y[lo][k]
__device__ __forceinline__ s8v ldfrag_full(const __hip_bfloat16* p0, const __hip_bfloat16* p1) {
    s4v a = *reinterpret_cast<const s4v*>(p0);
    s4v b = *reinterpret_cast<const s4v*>(p1);
    s8v r;
    r[0] = a[0]; r[1] = a[1]; r[2] = a[2]; r[3] = a[3];
    r[4] = b[0]; r[5] = b[1]; r[6] = b[2]; r[7] = b[3];
    return r;
}
// W-fragment for C = A @ W: F(W^T tile ct, k-step ks), fp32 W scaled+rounded to bf16
__device__ __forceinline__ s8v wfrag_build(const float* __restrict__ W, int N, int ct, int ks,
                                           int lo, int hi, float scale) {
    s8v r;
    int n = ct * 16 + lo;
    int k0 = ks * 32 + 4 * hi;
#pragma unroll
    for (int j = 0; j < 4; ++j) {
        r[j]     = f2bf(W[(k0 + j) * N + n] * scale);
        r[4 + j] = f2bf(W[(k0 + 16 + j) * N + n] * scale);
    }
    return r;
}

// ---------------------------------------------------------------------------
// K0: transpose x (fp32 [N,64]) -> xt (bf16 [64,N]) for q and v, per batch.
// ---------------------------------------------------------------------------
__global__ void xpose(const float* __restrict__ xq, const float* __restrict__ xv,
                      __hip_bfloat16* __restrict__ xtq, __hip_bfloat16* __restrict__ xtv) {
    __shared__ short ts[64][65];
    int m = blockIdx.y;
    int qv = m >> 1, b = m & 1;
    int l0 = blockIdx.x * 64;
    const float* x = (qv ? xv : xq) + (size_t)b * N_ * 64;
    int t = threadIdx.x;
#pragma unroll
    for (int i = 0; i < 4; ++i) {
        int f = t + i * 256;            // float4 idx 0..1023
        int r = f >> 4, c4 = f & 15;
        float4 v = *reinterpret_cast<const float4*>(x + (size_t)(l0 + r) * 64 + c4 * 4);
        ts[c4 * 4 + 0][r] = f2bf(v.x);
        ts[c4 * 4 + 1][r] = f2bf(v.y);
        ts[c4 * 4 + 2][r] = f2bf(v.z);
        ts[c4 * 4 + 3][r] = f2bf(v.w);
    }
    __syncthreads();
    short* xt = reinterpret_cast<short*>(qv ? xtv : xtq) + (size_t)b * 64 * N_;
#pragma unroll
    for (int i = 0; i < 4; ++i) {
        int f = t + i * 256;
        int d = f >> 4, seg = f & 15;
        s4v o;
        o[0] = ts[d][seg * 4 + 0]; o[1] = ts[d][seg * 4 + 1];
        o[2] = ts[d][seg * 4 + 2]; o[3] = ts[d][seg * 4 + 3];
        *reinterpret_cast<s4v*>(xt + (size_t)d * N_ + l0 + seg * 4) = o;
    }
}

// ---------------------------------------------------------------------------
// K1: one diffusion hop via MFMA: C = adj @ X, per (b, q/v).  (R7 version)
// grid (64,2,2) x 256; wave = col-tile.
// ---------------------------------------------------------------------------
__global__ __launch_bounds__(256) void spmm_mfma(
        const float* __restrict__ adj_q, const float* __restrict__ adj_v,
        const __hip_bfloat16* __restrict__ xtq, const __hip_bfloat16* __restrict__ xtv,
        float* __restrict__ oq, float* __restrict__ ov,
        __hip_bfloat16* __restrict__ oqt, __hip_bfloat16* __restrict__ ovt, int writet) {
    const int lane = threadIdx.x & 63;
    const int w = threadIdx.x >> 6;          // col-tile 0..3
    const int lo = lane & 15, hi = lane >> 4;
    const int rt = blockIdx.x;               // row-tile 0..63
    const int qv = blockIdx.y, b = blockIdx.z;

    const float* adj = (qv ? adj_v : adj_q) + (size_t)b * N_ * N_ + (size_t)(rt * 16 + lo) * N_;
    const __hip_bfloat16* xt = (qv ? xtv : xtq) + ((size_t)b * 64 + w * 16 + lo) * N_;

    f32x4 acc = {0.f, 0.f, 0.f, 0.f};
#pragma unroll 8
    for (int ks = 0; ks < 32; ++ks) {
        int k0 = ks * 32;
        float4 a4 = *reinterpret_cast<const float4*>(adj + k0 + 4 * hi);
        float4 b4 = *reinterpret_cast<const float4*>(adj + k0 + 16 + 4 * hi);
        pk8 af;
        af.u[0] = cvt_pk_bf16(a4.x, a4.y); af.u[1] = cvt_pk_bf16(a4.z, a4.w);
        af.u[2] = cvt_pk_bf16(b4.x, b4.y); af.u[3] = cvt_pk_bf16(b4.z, b4.w);
        s8v xf = ldfrag_full(xt + k0 + 4 * hi, xt + k0 + 16 + 4 * hi);
        acc = __builtin_amdgcn_mfma_f32_16x16x32_bf16(xf, af.v, acc, 0, 0, 0);
    }
    float* o = (qv ? ov : oq) + ((size_t)b * N_ + rt * 16 + lo) * 64 + w * 16 + 4 * hi;
    *reinterpret_cast<f32x4*>(o) = acc;
    if (writet) {
        short* ot = reinterpret_cast<short*>(qv ? ovt : oqt) + (size_t)b * 64 * N_;
#pragma unroll
        for (int j = 0; j < 4; ++j)
            ot[(size_t)(w * 16 + 4 * hi + j) * N_ + rt * 16 + lo] = f2bf(acc[j]);
    }
}

// ---------------------------------------------------------------------------
// K2: concat along node axis + LayerNorm(eps=1e-5, no affine).
// ---------------------------------------------------------------------------
__global__ void concat_ln(const float* __restrict__ qx, const float* __restrict__ q1,
                          const float* __restrict__ q2,
                          const float* __restrict__ vx, const float* __restrict__ v1,
                          const float* __restrict__ v2,
                          float* __restrict__ qc,
                          __hip_bfloat16* __restrict__ qcb, __hip_bfloat16* __restrict__ vcb) {
    int rid  = blockIdx.x * 4 + (threadIdx.x >> 6);
    int lane = threadIdx.x & 63;
    int qvsel = rid >= (B_ * L_);
    int r = qvsel ? rid - B_ * L_ : rid;
    int b = r / L_, l = r % L_;
    int s = l / N_, i = l % N_;
    const float* src;
    if (!qvsel) src = (s == 0) ? qx : (s == 1) ? q1 : q2;
    else        src = (s == 0) ? vx : (s == 1) ? v1 : v2;
    float v = src[((size_t)b * N_ + i) * D_ + lane];
    float mean = wave_sum64(v) * (1.0f / 64.0f);
    float d = v - mean;
    float var = wave_sum64(d * d) * (1.0f / 64.0f);
    float y = d * rsqrtf(var + 1e-5f);
    size_t o = ((size_t)b * L_ + l) * D_ + lane;
    if (!qvsel) {
        qc[o] = y;
        reinterpret_cast<short*>(qcb)[o] = f2bf(y);
    } else {
        reinterpret_cast<short*>(vcb)[o] = f2bf(y);
    }
}

// ---------------------------------------------------------------------------
// K3: fused qkv projection, MFMA, writing MFMA-native PACKED layouts:
//   qpk/kpk[bh][t32][lane][8]: slots 0-3 = rows t*32+lo (half 0), 4-7 = +16 (half 1)
//     entry: Mat[row][dk=4hi+j] -> one 16B dwordx4 per lane per 32-tile in attn.
//   vpk[bh][t32][lane(hi',lo')][8]: slot s = V[t*32+kmap(hi',s)][dv=lo'].
// 12 col-tiles: [wq:4 | wk:4 | wv:4]; grid 192 x 256.
// ---------------------------------------------------------------------------
__global__ __launch_bounds__(256) void gemm_qkv(
        const __hip_bfloat16* __restrict__ qcb, const __hip_bfloat16* __restrict__ vcb,
        const float* __restrict__ wq, const float* __restrict__ wk, const float* __restrict__ wv,
        __hip_bfloat16* __restrict__ qpk, __hip_bfloat16* __restrict__ kpk,
        __hip_bfloat16* __restrict__ vpk) {
    const int w = threadIdx.x >> 6;
    const int lane = threadIdx.x & 63;
    const int lo = lane & 15, hi = lane >> 4;
    const int ct0 = w * 3;

    s8v wf[3][2];
#pragma unroll
    for (int c = 0; c < 3; ++c) {
        int ct = ct0 + c;
        const float* W = (ct < 4) ? wq : (ct < 8) ? wk : wv;
        float sc = (ct < 4) ? QSCALE : 1.0f;
        wf[c][0] = wfrag_build(W, 64, ct & 3, 0, lo, hi, sc);
        wf[c][1] = wfrag_build(W, 64, ct & 3, 1, lo, hi, sc);
    }
    const bool needq = (ct0 < 8);
    const bool needv = (ct0 + 2 >= 8);
    const f32x4 zz = {0.f, 0.f, 0.f, 0.f};

#pragma unroll
    for (int rr = 0; rr < 2; ++rr) {
        int rt = blockIdx.x * 2 + rr;        // 16-row tile, 0..383
        int rbase = rt * 16;
        int b = rbase / L_;
        int lloc = rbase % L_;               // local row base within batch
        int t32 = lloc >> 5;                 // 32-tile 0..95
        int half = (lloc >> 4) & 1;
        s8v aq0, aq1, av0, av1;
        if (needq) {
            const __hip_bfloat16* ar = qcb + (size_t)(rbase + lo) * 64;
            aq0 = ldfrag_full(ar + 4 * hi, ar + 16 + 4 * hi);
            aq1 = ldfrag_full(ar + 32 + 4 * hi, ar + 48 + 4 * hi);
        }
        if (needv) {
            const __hip_bfloat16* ar = vcb + (size_t)(rbase + lo) * 64;
            av0 = ldfrag_full(ar + 4 * hi, ar + 16 + 4 * hi);
            av1 = ldfrag_full(ar + 32 + 4 * hi, ar + 48 + 4 * hi);
        }
#pragma unroll
        for (int c = 0; c < 3; ++c) {
            int ct = ct0 + c;
            f32x4 acc = zz;
            if (ct < 8) {
                acc = __builtin_amdgcn_mfma_f32_16x16x32_bf16(wf[c][0], aq0, acc, 0, 0, 0);
                acc = __builtin_amdgcn_mfma_f32_16x16x32_bf16(wf[c][1], aq1, acc, 0, 0, 0);
                int h = ct & 3;
                int bh = b * H_ + h;
                short* dst = reinterpret_cast<short*>((ct < 4) ? qpk : kpk);
                pk4 o;
                o.u[0] = cvt_pk_bf16(acc[0], acc[1]);
                o.u[1] = cvt_pk_bf16(acc[2], acc[3]);
                *reinterpret_cast<s4v*>(dst +
                    (((size_t)bh * 96 + t32) * 64 + lane) * 8 + half * 4) = o.v;
            } else {
                acc = __builtin_amdgcn_mfma_f32_16x16x32_bf16(wf[c][0], av0, acc, 0, 0, 0);
                acc = __builtin_amdgcn_mfma_f32_16x16x32_bf16(wf[c][1], av1, acc, 0, 0, 0);
                int h = ct - 8;
                int bh = b * H_ + h;
                short* vt = reinterpret_cast<short*>(vpk);
                // producer lane (hi,lo) reg j = V[row=lloc+lo][dv=4hi+j]
                // -> consumer lane' = (hi'=lo>>2, lo'=4hi+j), slot = half*4 + (lo&3)
                size_t base = ((size_t)bh * 96 + t32) * 64 * 8;
#pragma unroll
                for (int j = 0; j < 4; ++j) {
                    int lanep = (lo >> 2) * 16 + (4 * hi + j);
                    vt[base + (size_t)lanep * 8 + half * 4 + (lo & 3)] = f2bf(acc[j]);
                }
            }
        }
    }
}

// ---------------------------------------------------------------------------
// K4: MFMA flash attention, fixed-max softmax, PACKED operands.
// 4 waves = 4 key-groups; each wave processes BOTH q-tiles of the 32-row pair.
// Per 32-key tile: 1 dwordx4 K load + 1 dwordx4 V load (contiguous 1KB/wave).
// Pure-sum LDS merge. grid 768 x 256. Output bf16.
// ---------------------------------------------------------------------------
__global__ __launch_bounds__(256) void attn_mfma(
        const __hip_bfloat16* __restrict__ qpk, const __hip_bfloat16* __restrict__ kpk,
        const __hip_bfloat16* __restrict__ vpk, __hip_bfloat16* __restrict__ attnob) {
    const int lane = threadIdx.x & 63;
    const int kg = threadIdx.x >> 6;         // key-group 0..3
    const int g = blockIdx.x;                // 0..767
    const int bh = g / 96;
    const int tp = g % 96;                   // q-pair (32 rows)
    const int b = bh >> 2, h = bh & 3;
    const int lo = lane & 15, hi = lane >> 4;

    const s8v* kp = reinterpret_cast<const s8v*>(kpk) + ((size_t)bh * 96) * 64 + lane;
    const s8v* vp = reinterpret_cast<const s8v*>(vpk) + ((size_t)bh * 96) * 64 + lane;
    const s8v* qp = reinterpret_cast<const s8v*>(qpk) + ((size_t)bh * 96 + tp) * 64 + lane;

    // Q fragments for the two q-tiles (halves of the packed entry)
    s8v q8 = *qp;
    s8v qfA = {q8[0], q8[1], q8[2], q8[3], 0, 0, 0, 0};
    s8v qfB = {q8[4], q8[5], q8[6], q8[7], 0, 0, 0, 0};

    f32x4 accA = {0.f, 0.f, 0.f, 0.f}, accB = {0.f, 0.f, 0.f, 0.f};
    float lsA = 0.f, lsB = 0.f;
    const f32x4 zz = {0.f, 0.f, 0.f, 0.f};

    const int t0 = kg * 24, t1 = t0 + 24;    // 24 x 32-key tiles
    s8v kf8 = kp[(size_t)t0 * 64];
    s8v vf8 = vp[(size_t)t0 * 64];

    for (int t = t0; t < t1; ++t) {
        s8v ck = kf8, cv = vf8;
        int nt = (t + 1 < t1) ? t + 1 : t0;
        kf8 = kp[(size_t)nt * 64];
        vf8 = vp[(size_t)nt * 64];

        s8v kf0 = {ck[0], ck[1], ck[2], ck[3], 0, 0, 0, 0};
        s8v kf1 = {ck[4], ck[5], ck[6], ck[7], 0, 0, 0, 0};

        f32x4 s0A = __builtin_amdgcn_mfma_f32_16x16x32_bf16(kf0, qfA, zz, 0, 0, 0);
        f32x4 s1A = __builtin_amdgcn_mfma_f32_16x16x32_bf16(kf1, qfA, zz, 0, 0, 0);
        f32x4 s0B = __builtin_amdgcn_mfma_f32_16x16x32_bf16(kf0, qfB, zz, 0, 0, 0);
        f32x4 s1B = __builtin_amdgcn_mfma_f32_16x16x32_bf16(kf1, qfB, zz, 0, 0, 0);

        float pA0 = EXP2F(s0A[0]), pA1 = EXP2F(s0A[1]), pA2 = EXP2F(s0A[2]), pA3 = EXP2F(s0A[3]);
        float pA4 = EXP2F(s1A[0]), pA5 = EXP2F(s1A[1]), pA6 = EXP2F(s1A[2]), pA7 = EXP2F(s1A[3]);
        float pB0 = EXP2F(s0B[0]), pB1 = EXP2F(s0B[1]), pB2 = EXP2F(s0B[2]), pB3 = EXP2F(s0B[3]);
        float pB4 = EXP2F(s1B[0]), pB5 = EXP2F(s1B[1]), pB6 = EXP2F(s1B[2]), pB7 = EXP2F(s1B[3]);
        lsA += ((pA0 + pA1) + (pA2 + pA3)) + ((pA4 + pA5) + (pA6 + pA7));
        lsB += ((pB0 + pB1) + (pB2 + pB3)) + ((pB4 + pB5) + (pB6 + pB7));

        pk8 pfA, pfB;
        pfA.u[0] = cvt_pk_bf16(pA0, pA1); pfA.u[1] = cvt_pk_bf16(pA2, pA3);
        pfA.u[2] = cvt_pk_bf16(pA4, pA5); pfA.u[3] = cvt_pk_bf16(pA6, pA7);
        pfB.u[0] = cvt_pk_bf16(pB0, pB1); pfB.u[1] = cvt_pk_bf16(pB2, pB3);
        pfB.u[2] = cvt_pk_bf16(pB4, pB5); pfB.u[3] = cvt_pk_bf16(pB6, pB7);

        accA = __builtin_amdgcn_mfma_f32_16x16x32_bf16(cv, pfA.v, accA, 0, 0, 0);
        accB = __builtin_amdgcn_mfma_f32_16x16x32_bf16(cv, pfB.v, accB, 0, 0, 0);
    }

    lsA += __shfl_xor(lsA, 16, 64); lsA += __shfl_xor(lsA, 32, 64);
    lsB += __shfl_xor(lsB, 16, 64); lsB += __shfl_xor(lsB, 32, 64);

    __shared__ float red[4][2][64][5];
    red[kg][0][lane][0] = accA[0]; red[kg][0][lane][1] = accA[1];
    red[kg][0][lane][2] = accA[2]; red[kg][0][lane][3] = accA[3];
    red[kg][0][lane][4] = lsA;
    red[kg][1][lane][0] = accB[0]; red[kg][1][lane][1] = accB[1];
    red[kg][1][lane][2] = accB[2]; red[kg][1][lane][3] = accB[3];
    red[kg][1][lane][4] = lsB;
    __syncthreads();
    if (kg < 2) {
        int t = kg;   // q-tile 0/1
        float a0 = 0.f, a1 = 0.f, a2 = 0.f, a3 = 0.f, lt = 0.f;
#pragma unroll
        for (int g2 = 0; g2 < 4; ++g2) {
            a0 += red[g2][t][lane][0];
            a1 += red[g2][t][lane][1];
            a2 += red[g2][t][lane][2];
            a3 += red[g2][t][lane][3];
            lt += red[g2][t][lane][4];
        }
        float inv = 1.0f / lt;
        pk4 o;
        o.u[0] = cvt_pk_bf16(a0 * inv, a1 * inv);
        o.u[1] = cvt_pk_bf16(a2 * inv, a3 * inv);
        *reinterpret_cast<s4v*>(reinterpret_cast<short*>(attnob) +
            ((size_t)b * L_ + tp * 32 + t * 16 + lo) * 64 + h * 16 + 4 * hi) = o.v;
    }
}

// ---------------------------------------------------------------------------
// K5: o2 = LN( attnob @ w_fc + qc ; mha_ln, eps 1e-6 ), MFMA. grid 96 x 256.
// ---------------------------------------------------------------------------
__global__ __launch_bounds__(256) void gemm_fc_ln(
        const __hip_bfloat16* __restrict__ attnob, const float* __restrict__ qc,
        const float* __restrict__ wfc,
        const float* __restrict__ lnw, const float* __restrict__ lnb,
        float* __restrict__ o2) {
    const int rt = blockIdx.x * 4 + (threadIdx.x >> 6);   // 0..383
    const int lane = threadIdx.x & 63;
    const int lo = lane & 15, hi = lane >> 4;
    const f32x4 zz = {0.f, 0.f, 0.f, 0.f};

    s8v wf[4][2];
#pragma unroll
    for (int ct = 0; ct < 4; ++ct) {
        wf[ct][0] = wfrag_build(wfc, 64, ct, 0, lo, hi, 1.0f);
        wf[ct][1] = wfrag_build(wfc, 64, ct, 1, lo, hi, 1.0f);
    }
    const __hip_bfloat16* ar = attnob + (size_t)(rt * 16 + lo) * 64;
    s8v a0 = ldfrag_full(ar + 4 * hi, ar + 16 + 4 * hi);
    s8v a1 = ldfrag_full(ar + 32 + 4 * hi, ar + 48 + 4 * hi);

    f32x4 acc[4];
    const int row = rt * 16 + lo;
#pragma unroll
    for (int ct = 0; ct < 4; ++ct) {
        acc[ct] = zz;
        acc[ct] = __builtin_amdgcn_mfma_f32_16x16x32_bf16(wf[ct][0], a0, acc[ct], 0, 0, 0);
        acc[ct] = __builtin_amdgcn_mfma_f32_16x16x32_bf16(wf[ct][1], a1, acc[ct], 0, 0, 0);
        f32x4 rq = *reinterpret_cast<const f32x4*>(qc + (size_t)row * 64 + ct * 16 + 4 * hi);
        acc[ct][0] += rq[0]; acc[ct][1] += rq[1]; acc[ct][2] += rq[2]; acc[ct][3] += rq[3];
    }
    float s = 0.f;
#pragma unroll
    for (int ct = 0; ct < 4; ++ct) s += (acc[ct][0] + acc[ct][1]) + (acc[ct][2] + acc[ct][3]);
    s += __shfl_xor(s, 16, 64); s += __shfl_xor(s, 32, 64);
    float mean = s * (1.0f / 64.0f);
    float vs = 0.f;
#pragma unroll
    for (int ct = 0; ct < 4; ++ct) {
#pragma unroll
        for (int j = 0; j < 4; ++j) { float d = acc[ct][j] - mean; vs += d * d; }
    }
    vs += __shfl_xor(vs, 16, 64); vs += __shfl_xor(vs, 32, 64);
    float rsq = rsqrtf(vs * (1.0f / 64.0f) + 1e-6f);
#pragma unroll
    for (int ct = 0; ct < 4; ++ct) {
        f32x4 w4 = *reinterpret_cast<const f32x4*>(lnw + ct * 16 + 4 * hi);
        f32x4 b4 = *reinterpret_cast<const f32x4*>(lnb + ct * 16 + 4 * hi);
        f32x4 o;
#pragma unroll
        for (int j = 0; j < 4; ++j) o[j] = (acc[ct][j] - mean) * rsq * w4[j] + b4[j];
        *reinterpret_cast<f32x4*>(o2 + (size_t)row * 64 + ct * 16 + 4 * hi) = o;
    }
}

// ---------------------------------------------------------------------------
// K6: pool: x[b,i,j] = mean_s o2flat[b, 192 i + 3 j + s] -> xb bf16 [2048,64].
// ---------------------------------------------------------------------------
__global__ void pool_k(const float* __restrict__ o2, __hip_bfloat16* __restrict__ xb) {
    int rid  = blockIdx.x * 4 + (threadIdx.x >> 6);  // b*N + i
    int lane = threadIdx.x & 63;
    int b = rid / N_, i = rid % N_;
    const float* ob = o2 + (size_t)b * L_ * 64 + (size_t)192 * i;
    int t = 3 * lane;
    float xv = (ob[t] + ob[t + 1] + ob[t + 2]) * (1.0f / 3.0f);
    reinterpret_cast<short*>(xb)[(size_t)rid * 64 + lane] = f2bf(xv);
}

// ---------------------------------------------------------------------------
// K7: x1 = relu( xb @ conv_w + conv_b ) -> bf16 [2048,128], MFMA. grid 128.
// ---------------------------------------------------------------------------
__global__ __launch_bounds__(256) void gemm_conv(
        const __hip_bfloat16* __restrict__ xb, const float* __restrict__ convw,
        const float* __restrict__ convb, __hip_bfloat16* __restrict__ x1b) {
    const int w = threadIdx.x >> 6;
    const int lane = threadIdx.x & 63;
    const int lo = lane & 15, hi = lane >> 4;
    const int rt = blockIdx.x;               // 0..127
    const f32x4 zz = {0.f, 0.f, 0.f, 0.f};

    s8v wf[2][2];
#pragma unroll
    for (int c = 0; c < 2; ++c) {
        int ct = 2 * w + c;
        wf[c][0] = wfrag_build(convw, 128, ct, 0, lo, hi, 1.0f);
        wf[c][1] = wfrag_build(convw, 128, ct, 1, lo, hi, 1.0f);
    }
    const __hip_bfloat16* ar = xb + (size_t)(rt * 16 + lo) * 64;
    s8v a0 = ldfrag_full(ar + 4 * hi, ar + 16 + 4 * hi);
    s8v a1 = ldfrag_full(ar + 32 + 4 * hi, ar + 48 + 4 * hi);

#pragma unroll
    for (int c = 0; c < 2; ++c) {
        int ct = 2 * w + c;
        f32x4 acc = zz;
        acc = __builtin_amdgcn_mfma_f32_16x16x32_bf16(wf[c][0], a0, acc, 0, 0, 0);
        acc = __builtin_amdgcn_mfma_f32_16x16x32_bf16(wf[c][1], a1, acc, 0, 0, 0);
        f32x4 bia = *reinterpret_cast<const f32x4*>(convb + ct * 16 + 4 * hi);
        pk4 o;
        o.u[0] = cvt_pk_bf16(fmaxf(acc[0] + bia[0], 0.f), fmaxf(acc[1] + bia[1], 0.f));
        o.u[1] = cvt_pk_bf16(fmaxf(acc[2] + bia[2], 0.f), fmaxf(acc[3] + bia[3], 0.f));
        *reinterpret_cast<s4v*>(reinterpret_cast<short*>(x1b) +
            (size_t)(rt * 16 + lo) * 128 + ct * 16 + 4 * hi) = o.v;
    }
}

// ---------------------------------------------------------------------------
// K8: out = LN( q_x + x1b @ lin_w + lin_b ; norm, eps 1e-5 ), MFMA, K=128.
// ---------------------------------------------------------------------------
__global__ __launch_bounds__(256) void gemm_lin_ln(
        const __hip_bfloat16* __restrict__ x1b, const float* __restrict__ qx,
        const float* __restrict__ linw, const float* __restrict__ linb,
        const float* __restrict__ nw, const float* __restrict__ nb,
        float* __restrict__ out) {
    const int rt = blockIdx.x * 4 + (threadIdx.x >> 6);   // 0..127
    const int lane = threadIdx.x & 63;
    const int lo = lane & 15, hi = lane >> 4;
    const f32x4 zz = {0.f, 0.f, 0.f, 0.f};

    s8v wf[4][4];
#pragma unroll
    for (int ct = 0; ct < 4; ++ct)
#pragma unroll
        for (int ks = 0; ks < 4; ++ks)
            wf[ct][ks] = wfrag_build(linw, 64, ct, ks, lo, hi, 1.0f);

    const __hip_bfloat16* ar = x1b + (size_t)(rt * 16 + lo) * 128;
    s8v af[4];
#pragma unroll
    for (int ks = 0; ks < 4; ++ks)
        af[ks] = ldfrag_full(ar + ks * 32 + 4 * hi, ar + ks * 32 + 16 + 4 * hi);

    f32x4 acc[4];
    const int row = rt * 16 + lo;
#pragma unroll
    for (int ct = 0; ct < 4; ++ct) {
        acc[ct] = zz;
#pragma unroll
        for (int ks = 0; ks < 4; ++ks)
            acc[ct] = __builtin_amdgcn_mfma_f32_16x16x32_bf16(wf[ct][ks], af[ks], acc[ct], 0, 0, 0);
        f32x4 bia = *reinterpret_cast<const f32x4*>(linb + ct * 16 + 4 * hi);
        f32x4 rq  = *reinterpret_cast<const f32x4*>(qx + (size_t)row * 64 + ct * 16 + 4 * hi);
#pragma unroll
        for (int j = 0; j < 4; ++j) acc[ct][j] += bia[j] + rq[j];
    }
    float s = 0.f;
#pragma unroll
    for (int ct = 0; ct < 4; ++ct) s += (acc[ct][0] + acc[ct][1]) + (acc[ct][2] + acc[ct][3]);
    s += __shfl_xor(s, 16, 64); s += __shfl_xor(s, 32, 64);
    float mean = s * (1.0f / 64.0f);
    float vs = 0.f;
#pragma unroll
    for (int ct = 0; ct < 4; ++ct) {
#pragma unroll
        for (int j = 0; j < 4; ++j) { float d = acc[ct][j] - mean; vs += d * d; }
    }
    vs += __shfl_xor(vs, 16, 64); vs += __shfl_xor(vs, 32, 64);
    float rsq = rsqrtf(vs * (1.0f / 64.0f) + 1e-5f);
#pragma unroll
    for (int ct = 0; ct < 4; ++ct) {
        f32x4 w4 = *reinterpret_cast<const f32x4*>(nw + ct * 16 + 4 * hi);
        f32x4 b4 = *reinterpret_cast<const f32x4*>(nb + ct * 16 + 4 * hi);
        f32x4 o;
#pragma unroll
        for (int j = 0; j < 4; ++j) o[j] = (acc[ct][j] - mean) * rsq * w4[j] + b4[j];
        *reinterpret_cast<f32x4*>(out + (size_t)row * 64 + ct * 16 + 4 * hi) = o;
    }
}

// ---------------------------------------------------------------------------
extern "C" void kernel_launch(void* const* d_in, const int* in_sizes, int n_in,
                              void* d_out, int out_size, void* d_ws, size_t ws_size,
                              hipStream_t stream) {
    const float* q_x      = (const float*)d_in[0];
    const float* q_adj    = (const float*)d_in[1];
    const float* v_x      = (const float*)d_in[2];
    const float* v_adj    = (const float*)d_in[3];
    const float* w_qs     = (const float*)d_in[4];
    const float* w_ks     = (const float*)d_in[5];
    const float* w_vs     = (const float*)d_in[6];
    const float* w_fc     = (const float*)d_in[7];
    const float* mha_ln_w = (const float*)d_in[8];
    const float* mha_ln_b = (const float*)d_in[9];
    const float* conv_w   = (const float*)d_in[10];
    const float* conv_b   = (const float*)d_in[11];
    const float* lin_w    = (const float*)d_in[12];
    const float* lin_b    = (const float*)d_in[13];
    const float* norm_w   = (const float*)d_in[14];
    const float* norm_b   = (const float*)d_in[15];

    float* ws = (float*)d_ws;
    float* q1    = ws;                 // 131072 f each
    float* v1    = q1 + 131072;
    float* q2    = v1 + 131072;
    float* v2    = q2 + 131072;
    float* qc    = v2 + 131072;        // 393216 f
    float* o2    = qc + 393216;        // 393216 f
    __hip_bfloat16* qcb    = (__hip_bfloat16*)(o2 + 393216);   // 393216 bf16 each
    __hip_bfloat16* vcb    = qcb + 393216;
    __hip_bfloat16* qpk    = vcb + 393216;                     // [BH,96,64,8] packed
    __hip_bfloat16* kpk    = qpk + 393216;
    __hip_bfloat16* vpk    = kpk + 393216;
    __hip_bfloat16* attnob = vpk + 393216;                     // [B*L,64]
    __hip_bfloat16* xtq    = attnob + 393216;                  // [B,64,1024] bf16
    __hip_bfloat16* xtv    = xtq + 131072;
    __hip_bfloat16* q1t    = xtv + 131072;
    __hip_bfloat16* v1t    = q1t + 131072;
    __hip_bfloat16* xb     = v1t + 131072;                     // [2048,64]
    __hip_bfloat16* x1b    = xb + 131072;                      // [2048,128]
    float* out   = (float*)d_out;

    xpose<<<dim3(16, 4), 256, 0, stream>>>(q_x, v_x, xtq, xtv);
    spmm_mfma<<<dim3(64, 2, 2), 256, 0, stream>>>(q_adj, v_adj, xtq, xtv,
                                                  q1, v1, q1t, v1t, 1);
    spmm_mfma<<<dim3(64, 2, 2), 256, 0, stream>>>(q_adj, v_adj, q1t, v1t,
                                                  q2, v2, nullptr, nullptr, 0);
    concat_ln<<<3072, 256, 0, stream>>>(q_x, q1, q2, v_x, v1, v2, qc, qcb, vcb);
    gemm_qkv<<<192, 256, 0, stream>>>(qcb, vcb, w_qs, w_ks, w_vs, qpk, kpk, vpk);
    attn_mfma<<<768, 256, 0, stream>>>(qpk, kpk, vpk, attnob);
    gemm_fc_ln<<<96, 256, 0, stream>>>(attnob, qc, w_fc, mha_ln_w, mha_ln_b, o2);
    pool_k<<<512, 256, 0, stream>>>(o2, xb);
    gemm_conv<<<128, 256, 0, stream>>>(xb, conv_w, conv_b, x1b);
    gemm_lin_ln<<<32, 256, 0, stream>>>(x1b, q_x, lin_w, lin_b, norm_w, norm_b, out);
}

// Round 11
// 163.639 us; speedup vs baseline: 1.1821x; 1.0322x over previous
//
#include <hip/hip_runtime.h>
#include <hip/hip_bf16.h>

#define B_ 2
#define N_ 1024
#define D_ 64
#define L_ 3072
#define H_ 4

typedef __attribute__((ext_vector_type(8))) short s8v;
typedef __attribute__((ext_vector_type(4))) short s4v;
typedef __attribute__((ext_vector_type(4))) float f32x4;

#define EXP2F(x) __builtin_amdgcn_exp2f(x)
#define QSCALE 0.36067376022224085f   // 0.25 * log2(e)

__device__ __forceinline__ float wave_sum64(float v) {
#pragma unroll
    for (int off = 32; off > 0; off >>= 1) v += __shfl_xor(v, off, 64);
    return v;
}

// float -> bf16 bits, round-to-nearest-even (finite inputs only)
__device__ __forceinline__ short f2bf(float f) {
    unsigned u = __float_as_uint(f);
    u += 0x7FFFu + ((u >> 16) & 1u);
    return (short)(u >> 16);
}
// pack 2 floats -> 2 bf16 in one u32 (lo=a, hi=b), single VALU op
__device__ __forceinline__ unsigned cvt_pk_bf16(float a, float b) {
    unsigned r;
    asm("v_cvt_pk_bf16_f32 %0, %1, %2" : "=v"(r) : "v"(a), "v"(b));
    return r;
}
union pk8 { s8v v; unsigned u[4]; };
union pk4 { s4v v; unsigned u[2]; };

// MFMA fragment contract (HW-verified R4-R10):
//   frag F(Mat): F[lane(hi,lo)][s] = Mat[lo][kmap(hi,s)], kmap = 4hi+s (s<4), 16+4hi+s-4 (s>=4)
//   mfma(F(X), F(Y))[lane(hi,lo)][j] = sum_k X[4hi+j][k] * Y[lo][k]
__device__ __forceinline__ s8v ldfrag_full(const __hip_bfloat16* p0, const __hip_bfloat16* p1) {
    s4v a = *reinterpret_cast<const s4v*>(p0);
    s4v b = *reinterpret_cast<const s4v*>(p1);
    s8v r;
    r[0] = a[0]; r[1] = a[1]; r[2] = a[2]; r[3] = a[3];
    r[4] = b[0]; r[5] = b[1]; r[6] = b[2]; r[7] = b[3];
    return r;
}
// W-fragment for C = A @ W: F(W^T tile ct, k-step ks), fp32 W scaled+rounded to bf16
__device__ __forceinline__ s8v wfrag_build(const float* __restrict__ W, int N, int ct, int ks,
                                           int lo, int hi, float scale) {
    s8v r;
    int n = ct * 16 + lo;
    int k0 = ks * 32 + 4 * hi;
#pragma unroll
    for (int j = 0; j < 4; ++j) {
        r[j]     = f2bf(W[(k0 + j) * N + n] * scale);
        r[4 + j] = f2bf(W[(k0 + 16 + j) * N + n] * scale);
    }
    return r;
}

// ---------------------------------------------------------------------------
// K0: transpose x (fp32 [N,64]) -> xt (bf16 [64,N]) for q and v, per batch.
// ---------------------------------------------------------------------------
__global__ void xpose(const float* __restrict__ xq, const float* __restrict__ xv,
                      __hip_bfloat16* __restrict__ xtq, __hip_bfloat16* __restrict__ xtv) {
    __shared__ short ts[64][65];
    int m = blockIdx.y;
    int qv = m >> 1, b = m & 1;
    int l0 = blockIdx.x * 64;
    const float* x = (qv ? xv : xq) + (size_t)b * N_ * 64;
    int t = threadIdx.x;
#pragma unroll
    for (int i = 0; i < 4; ++i) {
        int f = t + i * 256;            // float4 idx 0..1023
        int r = f >> 4, c4 = f & 15;
        float4 v = *reinterpret_cast<const float4*>(x + (size_t)(l0 + r) * 64 + c4 * 4);
        ts[c4 * 4 + 0][r] = f2bf(v.x);
        ts[c4 * 4 + 1][r] = f2bf(v.y);
        ts[c4 * 4 + 2][r] = f2bf(v.z);
        ts[c4 * 4 + 3][r] = f2bf(v.w);
    }
    __syncthreads();
    short* xt = reinterpret_cast<short*>(qv ? xtv : xtq) + (size_t)b * 64 * N_;
#pragma unroll
    for (int i = 0; i < 4; ++i) {
        int f = t + i * 256;
        int d = f >> 4, seg = f & 15;
        s4v o;
        o[0] = ts[d][seg * 4 + 0]; o[1] = ts[d][seg * 4 + 1];
        o[2] = ts[d][seg * 4 + 2]; o[3] = ts[d][seg * 4 + 3];
        *reinterpret_cast<s4v*>(xt + (size_t)d * N_ + l0 + seg * 4) = o;
    }
}

// ---------------------------------------------------------------------------
// K1: one diffusion hop via MFMA: C = adj @ X, per (b, q/v).
// grid (64,2,2) x 256; wave = col-tile.
// ---------------------------------------------------------------------------
__global__ __launch_bounds__(256) void spmm_mfma(
        const float* __restrict__ adj_q, const float* __restrict__ adj_v,
        const __hip_bfloat16* __restrict__ xtq, const __hip_bfloat16* __restrict__ xtv,
        float* __restrict__ oq, float* __restrict__ ov,
        __hip_bfloat16* __restrict__ oqt, __hip_bfloat16* __restrict__ ovt, int writet) {
    const int lane = threadIdx.x & 63;
    const int w = threadIdx.x >> 6;          // col-tile 0..3
    const int lo = lane & 15, hi = lane >> 4;
    const int rt = blockIdx.x;               // row-tile 0..63
    const int qv = blockIdx.y, b = blockIdx.z;

    const float* adj = (qv ? adj_v : adj_q) + (size_t)b * N_ * N_ + (size_t)(rt * 16 + lo) * N_;
    const __hip_bfloat16* xt = (qv ? xtv : xtq) + ((size_t)b * 64 + w * 16 + lo) * N_;

    f32x4 acc = {0.f, 0.f, 0.f, 0.f};
#pragma unroll 8
    for (int ks = 0; ks < 32; ++ks) {
        int k0 = ks * 32;
        float4 a4 = *reinterpret_cast<const float4*>(adj + k0 + 4 * hi);
        float4 b4 = *reinterpret_cast<const float4*>(adj + k0 + 16 + 4 * hi);
        pk8 af;
        af.u[0] = cvt_pk_bf16(a4.x, a4.y); af.u[1] = cvt_pk_bf16(a4.z, a4.w);
        af.u[2] = cvt_pk_bf16(b4.x, b4.y); af.u[3] = cvt_pk_bf16(b4.z, b4.w);
        s8v xf = ldfrag_full(xt + k0 + 4 * hi, xt + k0 + 16 + 4 * hi);
        acc = __builtin_amdgcn_mfma_f32_16x16x32_bf16(xf, af.v, acc, 0, 0, 0);
    }
    float* o = (qv ? ov : oq) + ((size_t)b * N_ + rt * 16 + lo) * 64 + w * 16 + 4 * hi;
    *reinterpret_cast<f32x4*>(o) = acc;
    if (writet) {
        short* ot = reinterpret_cast<short*>(qv ? ovt : oqt) + (size_t)b * 64 * N_;
#pragma unroll
        for (int j = 0; j < 4; ++j)
            ot[(size_t)(w * 16 + 4 * hi + j) * N_ + rt * 16 + lo] = f2bf(acc[j]);
    }
}

// ---------------------------------------------------------------------------
// K2: concat along node axis + LayerNorm(eps=1e-5, no affine).
// ---------------------------------------------------------------------------
__global__ void concat_ln(const float* __restrict__ qx, const float* __restrict__ q1,
                          const float* __restrict__ q2,
                          const float* __restrict__ vx, const float* __restrict__ v1,
                          const float* __restrict__ v2,
                          float* __restrict__ qc,
                          __hip_bfloat16* __restrict__ qcb, __hip_bfloat16* __restrict__ vcb) {
    int rid  = blockIdx.x * 4 + (threadIdx.x >> 6);
    int lane = threadIdx.x & 63;
    int qvsel = rid >= (B_ * L_);
    int r = qvsel ? rid - B_ * L_ : rid;
    int b = r / L_, l = r % L_;
    int s = l / N_, i = l % N_;
    const float* src;
    if (!qvsel) src = (s == 0) ? qx : (s == 1) ? q1 : q2;
    else        src = (s == 0) ? vx : (s == 1) ? v1 : v2;
    float v = src[((size_t)b * N_ + i) * D_ + lane];
    float mean = wave_sum64(v) * (1.0f / 64.0f);
    float d = v - mean;
    float var = wave_sum64(d * d) * (1.0f / 64.0f);
    float y = d * rsqrtf(var + 1e-5f);
    size_t o = ((size_t)b * L_ + l) * D_ + lane;
    if (!qvsel) {
        qc[o] = y;
        reinterpret_cast<short*>(qcb)[o] = f2bf(y);
    } else {
        reinterpret_cast<short*>(vcb)[o] = f2bf(y);
    }
}

// ---------------------------------------------------------------------------
// K3: fused qkv projection, MFMA, writing MFMA-native PACKED layouts:
//   qpk/kpk[bh][t32][lane][8]: slots 0-3 = rows t*32+lo (half 0), 4-7 = +16 (half 1)
//   vpk[bh][t32][lane(hi',lo')][8]: slot s = V[t*32+kmap(hi',s)][dv=lo'].
// 12 col-tiles: [wq:4 | wk:4 | wv:4]; grid 192 x 256.
// ---------------------------------------------------------------------------
__global__ __launch_bounds__(256) void gemm_qkv(
        const __hip_bfloat16* __restrict__ qcb, const __hip_bfloat16* __restrict__ vcb,
        const float* __restrict__ wq, const float* __restrict__ wk, const float* __restrict__ wv,
        __hip_bfloat16* __restrict__ qpk, __hip_bfloat16* __restrict__ kpk,
        __hip_bfloat16* __restrict__ vpk) {
    const int w = threadIdx.x >> 6;
    const int lane = threadIdx.x & 63;
    const int lo = lane & 15, hi = lane >> 4;
    const int ct0 = w * 3;

    s8v wf[3][2];
#pragma unroll
    for (int c = 0; c < 3; ++c) {
        int ct = ct0 + c;
        const float* W = (ct < 4) ? wq : (ct < 8) ? wk : wv;
        float sc = (ct < 4) ? QSCALE : 1.0f;
        wf[c][0] = wfrag_build(W, 64, ct & 3, 0, lo, hi, sc);
        wf[c][1] = wfrag_build(W, 64, ct & 3, 1, lo, hi, sc);
    }
    const bool needq = (ct0 < 8);
    const bool needv = (ct0 + 2 >= 8);
    const f32x4 zz = {0.f, 0.f, 0.f, 0.f};

#pragma unroll
    for (int rr = 0; rr < 2; ++rr) {
        int rt = blockIdx.x * 2 + rr;        // 16-row tile, 0..383
        int rbase = rt * 16;
        int b = rbase / L_;
        int lloc = rbase % L_;               // local row base within batch
        int t32 = lloc >> 5;                 // 32-tile 0..95
        int half = (lloc >> 4) & 1;
        s8v aq0, aq1, av0, av1;
        if (needq) {
            const __hip_bfloat16* ar = qcb + (size_t)(rbase + lo) * 64;
            aq0 = ldfrag_full(ar + 4 * hi, ar + 16 + 4 * hi);
            aq1 = ldfrag_full(ar + 32 + 4 * hi, ar + 48 + 4 * hi);
        }
        if (needv) {
            const __hip_bfloat16* ar = vcb + (size_t)(rbase + lo) * 64;
            av0 = ldfrag_full(ar + 4 * hi, ar + 16 + 4 * hi);
            av1 = ldfrag_full(ar + 32 + 4 * hi, ar + 48 + 4 * hi);
        }
#pragma unroll
        for (int c = 0; c < 3; ++c) {
            int ct = ct0 + c;
            f32x4 acc = zz;
            if (ct < 8) {
                acc = __builtin_amdgcn_mfma_f32_16x16x32_bf16(wf[c][0], aq0, acc, 0, 0, 0);
                acc = __builtin_amdgcn_mfma_f32_16x16x32_bf16(wf[c][1], aq1, acc, 0, 0, 0);
                int h = ct & 3;
                int bh = b * H_ + h;
                short* dst = reinterpret_cast<short*>((ct < 4) ? qpk : kpk);
                pk4 o;
                o.u[0] = cvt_pk_bf16(acc[0], acc[1]);
                o.u[1] = cvt_pk_bf16(acc[2], acc[3]);
                *reinterpret_cast<s4v*>(dst +
                    (((size_t)bh * 96 + t32) * 64 + lane) * 8 + half * 4) = o.v;
            } else {
                acc = __builtin_amdgcn_mfma_f32_16x16x32_bf16(wf[c][0], av0, acc, 0, 0, 0);
                acc = __builtin_amdgcn_mfma_f32_16x16x32_bf16(wf[c][1], av1, acc, 0, 0, 0);
                int h = ct - 8;
                int bh = b * H_ + h;
                short* vt = reinterpret_cast<short*>(vpk);
                // producer lane (hi,lo) reg j = V[row=lloc+lo][dv=4hi+j]
                // -> consumer lane' = (hi'=lo>>2, lo'=4hi+j), slot = half*4 + (lo&3)
                size_t base = ((size_t)bh * 96 + t32) * 64 * 8;
#pragma unroll
                for (int j = 0; j < 4; ++j) {
                    int lanep = (lo >> 2) * 16 + (4 * hi + j);
                    vt[base + (size_t)lanep * 8 + half * 4 + (lo & 3)] = f2bf(acc[j]);
                }
            }
        }
    }
}

// ---------------------------------------------------------------------------
// K4: MFMA flash attention, fixed-max softmax, PACKED operands.
// 8 waves = 8 key-groups (12 x 32-key tiles each, fully unrolled), prefetch
// depth 2; each wave does BOTH q-tiles. Pure-sum merge (20KB LDS).
// grid 768 x 512. Output bf16.
// ---------------------------------------------------------------------------
__global__ __launch_bounds__(512) void attn_mfma(
        const __hip_bfloat16* __restrict__ qpk, const __hip_bfloat16* __restrict__ kpk,
        const __hip_bfloat16* __restrict__ vpk, __hip_bfloat16* __restrict__ attnob) {
    const int lane = threadIdx.x & 63;
    const int kg = threadIdx.x >> 6;         // key-group 0..7
    const int g = blockIdx.x;                // 0..767
    const int bh = g / 96;
    const int tp = g % 96;                   // q-pair (32 rows)
    const int b = bh >> 2, h = bh & 3;
    const int lo = lane & 15, hi = lane >> 4;

    const s8v* kp = reinterpret_cast<const s8v*>(kpk) + ((size_t)bh * 96) * 64 + lane;
    const s8v* vp = reinterpret_cast<const s8v*>(vpk) + ((size_t)bh * 96) * 64 + lane;
    const s8v* qp = reinterpret_cast<const s8v*>(qpk) + ((size_t)bh * 96 + tp) * 64 + lane;

    // Q fragments for the two q-tiles (halves of the packed entry)
    s8v q8 = *qp;
    s8v qfA = {q8[0], q8[1], q8[2], q8[3], 0, 0, 0, 0};
    s8v qfB = {q8[4], q8[5], q8[6], q8[7], 0, 0, 0, 0};

    f32x4 accA = {0.f, 0.f, 0.f, 0.f}, accB = {0.f, 0.f, 0.f, 0.f};
    float lsA = 0.f, lsB = 0.f;
    const f32x4 zz = {0.f, 0.f, 0.f, 0.f};

    const int t0 = kg * 12;                  // 12 x 32-key tiles per wave
    // prefetch depth 2 (static slots; loop fully unrolled so all indices const)
    s8v kb0 = kp[(size_t)(t0 + 0) * 64];
    s8v vb0 = vp[(size_t)(t0 + 0) * 64];
    s8v kb1 = kp[(size_t)(t0 + 1) * 64];
    s8v vb1 = vp[(size_t)(t0 + 1) * 64];

#pragma unroll
    for (int i = 0; i < 12; ++i) {
        s8v ck, cv;
        if ((i & 1) == 0) { ck = kb0; cv = vb0; }
        else              { ck = kb1; cv = vb1; }
        int pf = (i + 2 < 12) ? t0 + i + 2 : t0;   // wrap: reload cached tile, harmless
        if ((i & 1) == 0) { kb0 = kp[(size_t)pf * 64]; vb0 = vp[(size_t)pf * 64]; }
        else              { kb1 = kp[(size_t)pf * 64]; vb1 = vp[(size_t)pf * 64]; }

        s8v kf0 = {ck[0], ck[1], ck[2], ck[3], 0, 0, 0, 0};
        s8v kf1 = {ck[4], ck[5], ck[6], ck[7], 0, 0, 0, 0};

        f32x4 s0A = __builtin_amdgcn_mfma_f32_16x16x32_bf16(kf0, qfA, zz, 0, 0, 0);
        f32x4 s1A = __builtin_amdgcn_mfma_f32_16x16x32_bf16(kf1, qfA, zz, 0, 0, 0);
        f32x4 s0B = __builtin_amdgcn_mfma_f32_16x16x32_bf16(kf0, qfB, zz, 0, 0, 0);
        f32x4 s1B = __builtin_amdgcn_mfma_f32_16x16x32_bf16(kf1, qfB, zz, 0, 0, 0);

        float pA0 = EXP2F(s0A[0]), pA1 = EXP2F(s0A[1]), pA2 = EXP2F(s0A[2]), pA3 = EXP2F(s0A[3]);
        float pA4 = EXP2F(s1A[0]), pA5 = EXP2F(s1A[1]), pA6 = EXP2F(s1A[2]), pA7 = EXP2F(s1A[3]);
        float pB0 = EXP2F(s0B[0]), pB1 = EXP2F(s0B[1]), pB2 = EXP2F(s0B[2]), pB3 = EXP2F(s0B[3]);
        float pB4 = EXP2F(s1B[0]), pB5 = EXP2F(s1B[1]), pB6 = EXP2F(s1B[2]), pB7 = EXP2F(s1B[3]);
        lsA += ((pA0 + pA1) + (pA2 + pA3)) + ((pA4 + pA5) + (pA6 + pA7));
        lsB += ((pB0 + pB1) + (pB2 + pB3)) + ((pB4 + pB5) + (pB6 + pB7));

        pk8 pfA, pfB;
        pfA.u[0] = cvt_pk_bf16(pA0, pA1); pfA.u[1] = cvt_pk_bf16(pA2, pA3);
        pfA.u[2] = cvt_pk_bf16(pA4, pA5); pfA.u[3] = cvt_pk_bf16(pA6, pA7);
        pfB.u[0] = cvt_pk_bf16(pB0, pB1); pfB.u[1] = cvt_pk_bf16(pB2, pB3);
        pfB.u[2] = cvt_pk_bf16(pB4, pB5); pfB.u[3] = cvt_pk_bf16(pB6, pB7);

        accA = __builtin_amdgcn_mfma_f32_16x16x32_bf16(cv, pfA.v, accA, 0, 0, 0);
        accB = __builtin_amdgcn_mfma_f32_16x16x32_bf16(cv, pfB.v, accB, 0, 0, 0);
    }

    lsA += __shfl_xor(lsA, 16, 64); lsA += __shfl_xor(lsA, 32, 64);
    lsB += __shfl_xor(lsB, 16, 64); lsB += __shfl_xor(lsB, 32, 64);

    __shared__ float red[8][2][64][5];
    red[kg][0][lane][0] = accA[0]; red[kg][0][lane][1] = accA[1];
    red[kg][0][lane][2] = accA[2]; red[kg][0][lane][3] = accA[3];
    red[kg][0][lane][4] = lsA;
    red[kg][1][lane][0] = accB[0]; red[kg][1][lane][1] = accB[1];
    red[kg][1][lane][2] = accB[2]; red[kg][1][lane][3] = accB[3];
    red[kg][1][lane][4] = lsB;
    __syncthreads();
    if (kg < 2) {
        int t = kg;   // q-tile 0/1
        float a0 = 0.f, a1 = 0.f, a2 = 0.f, a3 = 0.f, lt = 0.f;
#pragma unroll
        for (int g2 = 0; g2 < 8; ++g2) {
            a0 += red[g2][t][lane][0];
            a1 += red[g2][t][lane][1];
            a2 += red[g2][t][lane][2];
            a3 += red[g2][t][lane][3];
            lt += red[g2][t][lane][4];
        }
        float inv = 1.0f / lt;
        pk4 o;
        o.u[0] = cvt_pk_bf16(a0 * inv, a1 * inv);
        o.u[1] = cvt_pk_bf16(a2 * inv, a3 * inv);
        *reinterpret_cast<s4v*>(reinterpret_cast<short*>(attnob) +
            ((size_t)b * L_ + tp * 32 + t * 16 + lo) * 64 + h * 16 + 4 * hi) = o.v;
    }
}

// ---------------------------------------------------------------------------
// K5: o2 = LN( attnob @ w_fc + qc ; mha_ln, eps 1e-6 ), MFMA. grid 96 x 256.
// ---------------------------------------------------------------------------
__global__ __launch_bounds__(256) void gemm_fc_ln(
        const __hip_bfloat16* __restrict__ attnob, const float* __restrict__ qc,
        const float* __restrict__ wfc,
        const float* __restrict__ lnw, const float* __restrict__ lnb,
        float* __restrict__ o2) {
    const int rt = blockIdx.x * 4 + (threadIdx.x >> 6);   // 0..383
    const int lane = threadIdx.x & 63;
    const int lo = lane & 15, hi = lane >> 4;
    const f32x4 zz = {0.f, 0.f, 0.f, 0.f};

    s8v wf[4][2];
#pragma unroll
    for (int ct = 0; ct < 4; ++ct) {
        wf[ct][0] = wfrag_build(wfc, 64, ct, 0, lo, hi, 1.0f);
        wf[ct][1] = wfrag_build(wfc, 64, ct, 1, lo, hi, 1.0f);
    }
    const __hip_bfloat16* ar = attnob + (size_t)(rt * 16 + lo) * 64;
    s8v a0 = ldfrag_full(ar + 4 * hi, ar + 16 + 4 * hi);
    s8v a1 = ldfrag_full(ar + 32 + 4 * hi, ar + 48 + 4 * hi);

    f32x4 acc[4];
    const int row = rt * 16 + lo;
#pragma unroll
    for (int ct = 0; ct < 4; ++ct) {
        acc[ct] = zz;
        acc[ct] = __builtin_amdgcn_mfma_f32_16x16x32_bf16(wf[ct][0], a0, acc[ct], 0, 0, 0);
        acc[ct] = __builtin_amdgcn_mfma_f32_16x16x32_bf16(wf[ct][1], a1, acc[ct], 0, 0, 0);
        f32x4 rq = *reinterpret_cast<const f32x4*>(qc + (size_t)row * 64 + ct * 16 + 4 * hi);
        acc[ct][0] += rq[0]; acc[ct][1] += rq[1]; acc[ct][2] += rq[2]; acc[ct][3] += rq[3];
    }
    float s = 0.f;
#pragma unroll
    for (int ct = 0; ct < 4; ++ct) s += (acc[ct][0] + acc[ct][1]) + (acc[ct][2] + acc[ct][3]);
    s += __shfl_xor(s, 16, 64); s += __shfl_xor(s, 32, 64);
    float mean = s * (1.0f / 64.0f);
    float vs = 0.f;
#pragma unroll
    for (int ct = 0; ct < 4; ++ct) {
#pragma unroll
        for (int j = 0; j < 4; ++j) { float d = acc[ct][j] - mean; vs += d * d; }
    }
    vs += __shfl_xor(vs, 16, 64); vs += __shfl_xor(vs, 32, 64);
    float rsq = rsqrtf(vs * (1.0f / 64.0f) + 1e-6f);
#pragma unroll
    for (int ct = 0; ct < 4; ++ct) {
        f32x4 w4 = *reinterpret_cast<const f32x4*>(lnw + ct * 16 + 4 * hi);
        f32x4 b4 = *reinterpret_cast<const f32x4*>(lnb + ct * 16 + 4 * hi);
        f32x4 o;
#pragma unroll
        for (int j = 0; j < 4; ++j) o[j] = (acc[ct][j] - mean) * rsq * w4[j] + b4[j];
        *reinterpret_cast<f32x4*>(o2 + (size_t)row * 64 + ct * 16 + 4 * hi) = o;
    }
}

// ---------------------------------------------------------------------------
// K6: pool: x[b,i,j] = mean_s o2flat[b, 192 i + 3 j + s] -> xb bf16 [2048,64].
// ---------------------------------------------------------------------------
__global__ void pool_k(const float* __restrict__ o2, __hip_bfloat16* __restrict__ xb) {
    int rid  = blockIdx.x * 4 + (threadIdx.x >> 6);  // b*N + i
    int lane = threadIdx.x & 63;
    int b = rid / N_, i = rid % N_;
    const float* ob = o2 + (size_t)b * L_ * 64 + (size_t)192 * i;
    int t = 3 * lane;
    float xv = (ob[t] + ob[t + 1] + ob[t + 2]) * (1.0f / 3.0f);
    reinterpret_cast<short*>(xb)[(size_t)rid * 64 + lane] = f2bf(xv);
}

// ---------------------------------------------------------------------------
// K7: x1 = relu( xb @ conv_w + conv_b ) -> bf16 [2048,128], MFMA. grid 128.
// ---------------------------------------------------------------------------
__global__ __launch_bounds__(256) void gemm_conv(
        const __hip_bfloat16* __restrict__ xb, const float* __restrict__ convw,
        const float* __restrict__ convb, __hip_bfloat16* __restrict__ x1b) {
    const int w = threadIdx.x >> 6;
    const int lane = threadIdx.x & 63;
    const int lo = lane & 15, hi = lane >> 4;
    const int rt = blockIdx.x;               // 0..127
    const f32x4 zz = {0.f, 0.f, 0.f, 0.f};

    s8v wf[2][2];
#pragma unroll
    for (int c = 0; c < 2; ++c) {
        int ct = 2 * w + c;
        wf[c][0] = wfrag_build(convw, 128, ct, 0, lo, hi, 1.0f);
        wf[c][1] = wfrag_build(convw, 128, ct, 1, lo, hi, 1.0f);
    }
    const __hip_bfloat16* ar = xb + (size_t)(rt * 16 + lo) * 64;
    s8v a0 = ldfrag_full(ar + 4 * hi, ar + 16 + 4 * hi);
    s8v a1 = ldfrag_full(ar + 32 + 4 * hi, ar + 48 + 4 * hi);

#pragma unroll
    for (int c = 0; c < 2; ++c) {
        int ct = 2 * w + c;
        f32x4 acc = zz;
        acc = __builtin_amdgcn_mfma_f32_16x16x32_bf16(wf[c][0], a0, acc, 0, 0, 0);
        acc = __builtin_amdgcn_mfma_f32_16x16x32_bf16(wf[c][1], a1, acc, 0, 0, 0);
        f32x4 bia = *reinterpret_cast<const f32x4*>(convb + ct * 16 + 4 * hi);
        pk4 o;
        o.u[0] = cvt_pk_bf16(fmaxf(acc[0] + bia[0], 0.f), fmaxf(acc[1] + bia[1], 0.f));
        o.u[1] = cvt_pk_bf16(fmaxf(acc[2] + bia[2], 0.f), fmaxf(acc[3] + bia[3], 0.f));
        *reinterpret_cast<s4v*>(reinterpret_cast<short*>(x1b) +
            (size_t)(rt * 16 + lo) * 128 + ct * 16 + 4 * hi) = o.v;
    }
}

// ---------------------------------------------------------------------------
// K8: out = LN( q_x + x1b @ lin_w + lin_b ; norm, eps 1e-5 ), MFMA, K=128.
// ---------------------------------------------------------------------------
__global__ __launch_bounds__(256) void gemm_lin_ln(
        const __hip_bfloat16* __restrict__ x1b, const float* __restrict__ qx,
        const float* __restrict__ linw, const float* __restrict__ linb,
        const float* __restrict__ nw, const float* __restrict__ nb,
        float* __restrict__ out) {
    const int rt = blockIdx.x * 4 + (threadIdx.x >> 6);   // 0..127
    const int lane = threadIdx.x & 63;
    const int lo = lane & 15, hi = lane >> 4;
    const f32x4 zz = {0.f, 0.f, 0.f, 0.f};

    s8v wf[4][4];
#pragma unroll
    for (int ct = 0; ct < 4; ++ct)
#pragma unroll
        for (int ks = 0; ks < 4; ++ks)
            wf[ct][ks] = wfrag_build(linw, 64, ct, ks, lo, hi, 1.0f);

    const __hip_bfloat16* ar = x1b + (size_t)(rt * 16 + lo) * 128;
    s8v af[4];
#pragma unroll
    for (int ks = 0; ks < 4; ++ks)
        af[ks] = ldfrag_full(ar + ks * 32 + 4 * hi, ar + ks * 32 + 16 + 4 * hi);

    f32x4 acc[4];
    const int row = rt * 16 + lo;
#pragma unroll
    for (int ct = 0; ct < 4; ++ct) {
        acc[ct] = zz;
#pragma unroll
        for (int ks = 0; ks < 4; ++ks)
            acc[ct] = __builtin_amdgcn_mfma_f32_16x16x32_bf16(wf[ct][ks], af[ks], acc[ct], 0, 0, 0);
        f32x4 bia = *reinterpret_cast<const f32x4*>(linb + ct * 16 + 4 * hi);
        f32x4 rq  = *reinterpret_cast<const f32x4*>(qx + (size_t)row * 64 + ct * 16 + 4 * hi);
#pragma unroll
        for (int j = 0; j < 4; ++j) acc[ct][j] += bia[j] + rq[j];
    }
    float s = 0.f;
#pragma unroll
    for (int ct = 0; ct < 4; ++ct) s += (acc[ct][0] + acc[ct][1]) + (acc[ct][2] + acc[ct][3]);
    s += __shfl_xor(s, 16, 64); s += __shfl_xor(s, 32, 64);
    float mean = s * (1.0f / 64.0f);
    float vs = 0.f;
#pragma unroll
    for (int ct = 0; ct < 4; ++ct) {
#pragma unroll
        for (int j = 0; j < 4; ++j) { float d = acc[ct][j] - mean; vs += d * d; }
    }
    vs += __shfl_xor(vs, 16, 64); vs += __shfl_xor(vs, 32, 64);
    float rsq = rsqrtf(vs * (1.0f / 64.0f) + 1e-5f);
#pragma unroll
    for (int ct = 0; ct < 4; ++ct) {
        f32x4 w4 = *reinterpret_cast<const f32x4*>(nw + ct * 16 + 4 * hi);
        f32x4 b4 = *reinterpret_cast<const f32x4*>(nb + ct * 16 + 4 * hi);
        f32x4 o;
#pragma unroll
        for (int j = 0; j < 4; ++j) o[j] = (acc[ct][j] - mean) * rsq * w4[j] + b4[j];
        *reinterpret_cast<f32x4*>(out + (size_t)row * 64 + ct * 16 + 4 * hi) = o;
    }
}

// ---------------------------------------------------------------------------
extern "C" void kernel_launch(void* const* d_in, const int* in_sizes, int n_in,
                              void* d_out, int out_size, void* d_ws, size_t ws_size,
                              hipStream_t stream) {
    const float* q_x      = (const float*)d_in[0];
    const float* q_adj    = (const float*)d_in[1];
    const float* v_x      = (const float*)d_in[2];
    const float* v_adj    = (const float*)d_in[3];
    const float* w_qs     = (const float*)d_in[4];
    const float* w_ks     = (const float*)d_in[5];
    const float* w_vs     = (const float*)d_in[6];
    const float* w_fc     = (const float*)d_in[7];
    const float* mha_ln_w = (const float*)d_in[8];
    const float* mha_ln_b = (const float*)d_in[9];
    const float* conv_w   = (const float*)d_in[10];
    const float* conv_b   = (const float*)d_in[11];
    const float* lin_w    = (const float*)d_in[12];
    const float* lin_b    = (const float*)d_in[13];
    const float* norm_w   = (const float*)d_in[14];
    const float* norm_b   = (const float*)d_in[15];

    float* ws = (float*)d_ws;
    float* q1    = ws;                 // 131072 f each
    float* v1    = q1 + 131072;
    float* q2    = v1 + 131072;
    float* v2    = q2 + 131072;
    float* qc    = v2 + 131072;        // 393216 f
    float* o2    = qc + 393216;        // 393216 f
    __hip_bfloat16* qcb    = (__hip_bfloat16*)(o2 + 393216);   // 393216 bf16 each
    __hip_bfloat16* vcb    = qcb + 393216;
    __hip_bfloat16* qpk    = vcb + 393216;                     // [BH,96,64,8] packed
    __hip_bfloat16* kpk    = qpk + 393216;
    __hip_bfloat16* vpk    = kpk + 393216;
    __hip_bfloat16* attnob = vpk + 393216;                     // [B*L,64]
    __hip_bfloat16* xtq    = attnob + 393216;                  // [B,64,1024] bf16
    __hip_bfloat16* xtv    = xtq + 131072;
    __hip_bfloat16* q1t    = xtv + 131072;
    __hip_bfloat16* v1t    = q1t + 131072;
    __hip_bfloat16* xb     = v1t + 131072;                     // [2048,64]
    __hip_bfloat16* x1b    = xb + 131072;                      // [2048,128]
    float* out   = (float*)d_out;

    xpose<<<dim3(16, 4), 256, 0, stream>>>(q_x, v_x, xtq, xtv);
    spmm_mfma<<<dim3(64, 2, 2), 256, 0, stream>>>(q_adj, v_adj, xtq, xtv,
                                                  q1, v1, q1t, v1t, 1);
    spmm_mfma<<<dim3(64, 2, 2), 256, 0, stream>>>(q_adj, v_adj, q1t, v1t,
                                                  q2, v2, nullptr, nullptr, 0);
    concat_ln<<<3072, 256, 0, stream>>>(q_x, q1, q2, v_x, v1, v2, qc, qcb, vcb);
    gemm_qkv<<<192, 256, 0, stream>>>(qcb, vcb, w_qs, w_ks, w_vs, qpk, kpk, vpk);
    attn_mfma<<<768, 512, 0, stream>>>(qpk, kpk, vpk, attnob);
    gemm_fc_ln<<<96, 256, 0, stream>>>(attnob, qc, w_fc, mha_ln_w, mha_ln_b, o2);
    pool_k<<<512, 256, 0, stream>>>(o2, xb);
    gemm_conv<<<128, 256, 0, stream>>>(xb, conv_w, conv_b, x1b);
    gemm_lin_ln<<<32, 256, 0, stream>>>(x1b, q_x, lin_w, lin_b, norm_w, norm_b, out);
}

// Round 12
// 153.010 us; speedup vs baseline: 1.2642x; 1.0695x over previous
//
#include <hip/hip_runtime.h>
#include <hip/hip_bf16.h>

#define B_ 2
#define N_ 1024
#define D_ 64
#define L_ 3072
#define H_ 4

typedef __attribute__((ext_vector_type(8))) short s8v;
typedef __attribute__((ext_vector_type(4))) short s4v;
typedef __attribute__((ext_vector_type(4))) float f32x4;

#define EXP2F(x) __builtin_amdgcn_exp2f(x)
#define QSCALE 0.36067376022224085f   // 0.25 * log2(e)

// float -> bf16 bits, round-to-nearest-even (finite inputs only)
__device__ __forceinline__ short f2bf(float f) {
    unsigned u = __float_as_uint(f);
    u += 0x7FFFu + ((u >> 16) & 1u);
    return (short)(u >> 16);
}
// pack 2 floats -> 2 bf16 in one u32 (lo=a, hi=b), single VALU op
__device__ __forceinline__ unsigned cvt_pk_bf16(float a, float b) {
    unsigned r;
    asm("v_cvt_pk_bf16_f32 %0, %1, %2" : "=v"(r) : "v"(a), "v"(b));
    return r;
}
union pk8 { s8v v; unsigned u[4]; };
union pk4 { s4v v; unsigned u[2]; };

// MFMA fragment contract (HW-verified R4-R11):
//   frag F(Mat): F[lane(hi,lo)][s] = Mat[lo][kmap(hi,s)], kmap = 4hi+s (s<4), 16+4hi+s-4 (s>=4)
//   mfma(F(X), F(Y))[lane(hi,lo)][j] = sum_k X[4hi+j][k] * Y[lo][k]
__device__ __forceinline__ s8v ldfrag_full(const __hip_bfloat16* p0, const __hip_bfloat16* p1) {
    s4v a = *reinterpret_cast<const s4v*>(p0);
    s4v b = *reinterpret_cast<const s4v*>(p1);
    s8v r;
    r[0] = a[0]; r[1] = a[1]; r[2] = a[2]; r[3] = a[3];
    r[4] = b[0]; r[5] = b[1]; r[6] = b[2]; r[7] = b[3];
    return r;
}
__device__ __forceinline__ s8v ldsfrag(const short* p0, const short* p1) {
    s4v a = *reinterpret_cast<const s4v*>(p0);
    s4v b = *reinterpret_cast<const s4v*>(p1);
    s8v r;
    r[0] = a[0]; r[1] = a[1]; r[2] = a[2]; r[3] = a[3];
    r[4] = b[0]; r[5] = b[1]; r[6] = b[2]; r[7] = b[3];
    return r;
}
// W-fragment for C = A @ W: F(W^T tile ct, k-step ks), fp32 W scaled+rounded to bf16
__device__ __forceinline__ s8v wfrag_build(const float* __restrict__ W, int N, int ct, int ks,
                                           int lo, int hi, float scale) {
    s8v r;
    int n = ct * 16 + lo;
    int k0 = ks * 32 + 4 * hi;
#pragma unroll
    for (int j = 0; j < 4; ++j) {
        r[j]     = f2bf(W[(k0 + j) * N + n] * scale);
        r[4 + j] = f2bf(W[(k0 + 16 + j) * N + n] * scale);
    }
    return r;
}

// ---------------------------------------------------------------------------
// K0: transpose x (fp32 [N,64]) -> xt (bf16 [64,N]) for q and v, per batch.
// ---------------------------------------------------------------------------
__global__ void xpose(const float* __restrict__ xq, const float* __restrict__ xv,
                      __hip_bfloat16* __restrict__ xtq, __hip_bfloat16* __restrict__ xtv) {
    __shared__ short ts[64][65];
    int m = blockIdx.y;
    int qv = m >> 1, b = m & 1;
    int l0 = blockIdx.x * 64;
    const float* x = (qv ? xv : xq) + (size_t)b * N_ * 64;
    int t = threadIdx.x;
#pragma unroll
    for (int i = 0; i < 4; ++i) {
        int f = t + i * 256;            // float4 idx 0..1023
        int r = f >> 4, c4 = f & 15;
        float4 v = *reinterpret_cast<const float4*>(x + (size_t)(l0 + r) * 64 + c4 * 4);
        ts[c4 * 4 + 0][r] = f2bf(v.x);
        ts[c4 * 4 + 1][r] = f2bf(v.y);
        ts[c4 * 4 + 2][r] = f2bf(v.z);
        ts[c4 * 4 + 3][r] = f2bf(v.w);
    }
    __syncthreads();
    short* xt = reinterpret_cast<short*>(qv ? xtv : xtq) + (size_t)b * 64 * N_;
#pragma unroll
    for (int i = 0; i < 4; ++i) {
        int f = t + i * 256;
        int d = f >> 4, seg = f & 15;
        s4v o;
        o[0] = ts[d][seg * 4 + 0]; o[1] = ts[d][seg * 4 + 1];
        o[2] = ts[d][seg * 4 + 2]; o[3] = ts[d][seg * 4 + 3];
        *reinterpret_cast<s4v*>(xt + (size_t)d * N_ + l0 + seg * 4) = o;
    }
}

// ---------------------------------------------------------------------------
// K1: one diffusion hop via MFMA: C = adj @ X, per (b, q/v).
// grid (64,2,2) x 256; wave = col-tile.  (256-thr form; 512-thr regressed R8)
// ---------------------------------------------------------------------------
__global__ __launch_bounds__(256) void spmm_mfma(
        const float* __restrict__ adj_q, const float* __restrict__ adj_v,
        const __hip_bfloat16* __restrict__ xtq, const __hip_bfloat16* __restrict__ xtv,
        float* __restrict__ oq, float* __restrict__ ov,
        __hip_bfloat16* __restrict__ oqt, __hip_bfloat16* __restrict__ ovt, int writet) {
    const int lane = threadIdx.x & 63;
    const int w = threadIdx.x >> 6;          // col-tile 0..3
    const int lo = lane & 15, hi = lane >> 4;
    const int rt = blockIdx.x;               // row-tile 0..63
    const int qv = blockIdx.y, b = blockIdx.z;

    const float* adj = (qv ? adj_v : adj_q) + (size_t)b * N_ * N_ + (size_t)(rt * 16 + lo) * N_;
    const __hip_bfloat16* xt = (qv ? xtv : xtq) + ((size_t)b * 64 + w * 16 + lo) * N_;

    f32x4 acc = {0.f, 0.f, 0.f, 0.f};
#pragma unroll 8
    for (int ks = 0; ks < 32; ++ks) {
        int k0 = ks * 32;
        float4 a4 = *reinterpret_cast<const float4*>(adj + k0 + 4 * hi);
        float4 b4 = *reinterpret_cast<const float4*>(adj + k0 + 16 + 4 * hi);
        pk8 af;
        af.u[0] = cvt_pk_bf16(a4.x, a4.y); af.u[1] = cvt_pk_bf16(a4.z, a4.w);
        af.u[2] = cvt_pk_bf16(b4.x, b4.y); af.u[3] = cvt_pk_bf16(b4.z, b4.w);
        s8v xf = ldfrag_full(xt + k0 + 4 * hi, xt + k0 + 16 + 4 * hi);
        acc = __builtin_amdgcn_mfma_f32_16x16x32_bf16(xf, af.v, acc, 0, 0, 0);
    }
    float* o = (qv ? ov : oq) + ((size_t)b * N_ + rt * 16 + lo) * 64 + w * 16 + 4 * hi;
    *reinterpret_cast<f32x4*>(o) = acc;
    if (writet) {
        short* ot = reinterpret_cast<short*>(qv ? ovt : oqt) + (size_t)b * 64 * N_;
#pragma unroll
        for (int j = 0; j < 4; ++j)
            ot[(size_t)(w * 16 + 4 * hi + j) * N_ + rt * 16 + lo] = f2bf(acc[j]);
    }
}

// ---------------------------------------------------------------------------
// K2 (FUSED concat_ln + gemm_qkv): per block = 32 concat rows.
// Phase A: LN of 32 q-rows + 32 v-rows (wave w: q/v half by w>=2, 16 rows,
//   4 lanes/row) -> bf16 rows in LDS, qc fp32 to global.
// Phase B: qkv projection MFMAs reading A-fragments from LDS; packed stores.
// grid 192 x 256.
// ---------------------------------------------------------------------------
__global__ __launch_bounds__(256) void gemm_qkv_ln(
        const float* __restrict__ qx, const float* __restrict__ q1, const float* __restrict__ q2,
        const float* __restrict__ vx, const float* __restrict__ v1, const float* __restrict__ v2,
        const float* __restrict__ wq, const float* __restrict__ wk, const float* __restrict__ wv,
        float* __restrict__ qc,
        __hip_bfloat16* __restrict__ qpk, __hip_bfloat16* __restrict__ kpk,
        __hip_bfloat16* __restrict__ vpk) {
    const int w = threadIdx.x >> 6;
    const int lane = threadIdx.x & 63;
    const int lo = lane & 15, hi = lane >> 4;
    const int rbase = blockIdx.x * 32;       // first concat row of this block

    __shared__ short qs[32][72];             // 144B row stride: 16B-aligned, <=2-way banks
    __shared__ short vs[32][72];

    // W fragments (strided global loads overlap the LN phase)
    const int ct0 = w * 3;
    s8v wf[3][2];
#pragma unroll
    for (int c = 0; c < 3; ++c) {
        int ct = ct0 + c;
        const float* W = (ct < 4) ? wq : (ct < 8) ? wk : wv;
        float sc = (ct < 4) ? QSCALE : 1.0f;
        wf[c][0] = wfrag_build(W, 64, ct & 3, 0, lo, hi, sc);
        wf[c][1] = wfrag_build(W, 64, ct & 3, 1, lo, hi, sc);
    }

    // ---- Phase A: LayerNorm, 16 rows per wave, 4 lanes per row ----
    {
        const int isv = (w >= 2);
        const int r = (w & 1) * 16 + (lane >> 2);   // local row 0..31
        const int cg = lane & 3;                    // 16-col group
        const int grow = rbase + r;                 // global concat row
        const int b = grow / L_;
        const int l = grow % L_;
        const int s = l / N_, i = l % N_;
        const float* src;
        if (!isv) src = (s == 0) ? qx : (s == 1) ? q1 : q2;
        else      src = (s == 0) ? vx : (s == 1) ? v1 : v2;
        const float* p = src + ((size_t)b * N_ + i) * 64 + cg * 16;
        f32x4 x0 = *reinterpret_cast<const f32x4*>(p);
        f32x4 x1 = *reinterpret_cast<const f32x4*>(p + 4);
        f32x4 x2 = *reinterpret_cast<const f32x4*>(p + 8);
        f32x4 x3 = *reinterpret_cast<const f32x4*>(p + 12);
        float sum = (x0[0]+x0[1]+x0[2]+x0[3]) + (x1[0]+x1[1]+x1[2]+x1[3])
                  + (x2[0]+x2[1]+x2[2]+x2[3]) + (x3[0]+x3[1]+x3[2]+x3[3]);
        sum += __shfl_xor(sum, 1, 64);
        sum += __shfl_xor(sum, 2, 64);
        float mean = sum * (1.0f / 64.0f);
        float vsum = 0.f;
        float y[16];
#pragma unroll
        for (int j = 0; j < 4; ++j) { float d = x0[j]-mean; y[j]    = d; vsum += d*d; }
#pragma unroll
        for (int j = 0; j < 4; ++j) { float d = x1[j]-mean; y[4+j]  = d; vsum += d*d; }
#pragma unroll
        for (int j = 0; j < 4; ++j) { float d = x2[j]-mean; y[8+j]  = d; vsum += d*d; }
#pragma unroll
        for (int j = 0; j < 4; ++j) { float d = x3[j]-mean; y[12+j] = d; vsum += d*d; }
        vsum += __shfl_xor(vsum, 1, 64);
        vsum += __shfl_xor(vsum, 2, 64);
        float rsq = rsqrtf(vsum * (1.0f / 64.0f) + 1e-5f);
#pragma unroll
        for (int j = 0; j < 16; ++j) y[j] *= rsq;
        pk8 pa, pb;
        pa.u[0] = cvt_pk_bf16(y[0], y[1]);  pa.u[1] = cvt_pk_bf16(y[2], y[3]);
        pa.u[2] = cvt_pk_bf16(y[4], y[5]);  pa.u[3] = cvt_pk_bf16(y[6], y[7]);
        pb.u[0] = cvt_pk_bf16(y[8], y[9]);  pb.u[1] = cvt_pk_bf16(y[10], y[11]);
        pb.u[2] = cvt_pk_bf16(y[12], y[13]); pb.u[3] = cvt_pk_bf16(y[14], y[15]);
        short* dst = (isv ? &vs[r][0] : &qs[r][0]) + cg * 16;
        *reinterpret_cast<s8v*>(dst)     = pa.v;
        *reinterpret_cast<s8v*>(dst + 8) = pb.v;
        if (!isv) {
            float* qcd = qc + (size_t)grow * 64 + cg * 16;
#pragma unroll
            for (int j = 0; j < 4; ++j) qcd[j]      = y[j];
#pragma unroll
            for (int j = 0; j < 4; ++j) qcd[4 + j]  = y[4 + j];
#pragma unroll
            for (int j = 0; j < 4; ++j) qcd[8 + j]  = y[8 + j];
#pragma unroll
            for (int j = 0; j < 4; ++j) qcd[12 + j] = y[12 + j];
        }
    }
    __syncthreads();

    // ---- Phase B: projections from LDS ----
    const f32x4 zz = {0.f, 0.f, 0.f, 0.f};
#pragma unroll
    for (int rr = 0; rr < 2; ++rr) {
        int rbase16 = rbase + rr * 16;       // global row base of 16-row tile
        int b = rbase16 / L_;
        int lloc = rbase16 % L_;
        int t32 = lloc >> 5;
        int half = (lloc >> 4) & 1;
        const short* arq = &qs[rr * 16 + lo][0];
        const short* arv = &vs[rr * 16 + lo][0];
        s8v aq0 = ldsfrag(arq + 4 * hi, arq + 16 + 4 * hi);
        s8v aq1 = ldsfrag(arq + 32 + 4 * hi, arq + 48 + 4 * hi);
        s8v av0 = ldsfrag(arv + 4 * hi, arv + 16 + 4 * hi);
        s8v av1 = ldsfrag(arv + 32 + 4 * hi, arv + 48 + 4 * hi);
#pragma unroll
        for (int c = 0; c < 3; ++c) {
            int ct = ct0 + c;
            f32x4 acc = zz;
            if (ct < 8) {
                acc = __builtin_amdgcn_mfma_f32_16x16x32_bf16(wf[c][0], aq0, acc, 0, 0, 0);
                acc = __builtin_amdgcn_mfma_f32_16x16x32_bf16(wf[c][1], aq1, acc, 0, 0, 0);
                int h = ct & 3;
                int bh = b * H_ + h;
                short* dst = reinterpret_cast<short*>((ct < 4) ? qpk : kpk);
                pk4 o;
                o.u[0] = cvt_pk_bf16(acc[0], acc[1]);
                o.u[1] = cvt_pk_bf16(acc[2], acc[3]);
                *reinterpret_cast<s4v*>(dst +
                    (((size_t)bh * 96 + t32) * 64 + lane) * 8 + half * 4) = o.v;
            } else {
                acc = __builtin_amdgcn_mfma_f32_16x16x32_bf16(wf[c][0], av0, acc, 0, 0, 0);
                acc = __builtin_amdgcn_mfma_f32_16x16x32_bf16(wf[c][1], av1, acc, 0, 0, 0);
                int h = ct - 8;
                int bh = b * H_ + h;
                short* vt = reinterpret_cast<short*>(vpk);
                size_t base = ((size_t)bh * 96 + t32) * 64 * 8;
#pragma unroll
                for (int j = 0; j < 4; ++j) {
                    int lanep = (lo >> 2) * 16 + (4 * hi + j);
                    vt[base + (size_t)lanep * 8 + half * 4 + (lo & 3)] = f2bf(acc[j]);
                }
            }
        }
    }
}

// ---------------------------------------------------------------------------
// K4: MFMA flash attention (unchanged from R11).
// ---------------------------------------------------------------------------
__global__ __launch_bounds__(512) void attn_mfma(
        const __hip_bfloat16* __restrict__ qpk, const __hip_bfloat16* __restrict__ kpk,
        const __hip_bfloat16* __restrict__ vpk, __hip_bfloat16* __restrict__ attnob) {
    const int lane = threadIdx.x & 63;
    const int kg = threadIdx.x >> 6;         // key-group 0..7
    const int g = blockIdx.x;                // 0..767
    const int bh = g / 96;
    const int tp = g % 96;                   // q-pair (32 rows)
    const int b = bh >> 2, h = bh & 3;
    const int lo = lane & 15, hi = lane >> 4;

    const s8v* kp = reinterpret_cast<const s8v*>(kpk) + ((size_t)bh * 96) * 64 + lane;
    const s8v* vp = reinterpret_cast<const s8v*>(vpk) + ((size_t)bh * 96) * 64 + lane;
    const s8v* qp = reinterpret_cast<const s8v*>(qpk) + ((size_t)bh * 96 + tp) * 64 + lane;

    s8v q8 = *qp;
    s8v qfA = {q8[0], q8[1], q8[2], q8[3], 0, 0, 0, 0};
    s8v qfB = {q8[4], q8[5], q8[6], q8[7], 0, 0, 0, 0};

    f32x4 accA = {0.f, 0.f, 0.f, 0.f}, accB = {0.f, 0.f, 0.f, 0.f};
    float lsA = 0.f, lsB = 0.f;
    const f32x4 zz = {0.f, 0.f, 0.f, 0.f};

    const int t0 = kg * 12;
    s8v kb0 = kp[(size_t)(t0 + 0) * 64];
    s8v vb0 = vp[(size_t)(t0 + 0) * 64];
    s8v kb1 = kp[(size_t)(t0 + 1) * 64];
    s8v vb1 = vp[(size_t)(t0 + 1) * 64];

#pragma unroll
    for (int i = 0; i < 12; ++i) {
        s8v ck, cv;
        if ((i & 1) == 0) { ck = kb0; cv = vb0; }
        else              { ck = kb1; cv = vb1; }
        int pf = (i + 2 < 12) ? t0 + i + 2 : t0;
        if ((i & 1) == 0) { kb0 = kp[(size_t)pf * 64]; vb0 = vp[(size_t)pf * 64]; }
        else              { kb1 = kp[(size_t)pf * 64]; vb1 = vp[(size_t)pf * 64]; }

        s8v kf0 = {ck[0], ck[1], ck[2], ck[3], 0, 0, 0, 0};
        s8v kf1 = {ck[4], ck[5], ck[6], ck[7], 0, 0, 0, 0};

        f32x4 s0A = __builtin_amdgcn_mfma_f32_16x16x32_bf16(kf0, qfA, zz, 0, 0, 0);
        f32x4 s1A = __builtin_amdgcn_mfma_f32_16x16x32_bf16(kf1, qfA, zz, 0, 0, 0);
        f32x4 s0B = __builtin_amdgcn_mfma_f32_16x16x32_bf16(kf0, qfB, zz, 0, 0, 0);
        f32x4 s1B = __builtin_amdgcn_mfma_f32_16x16x32_bf16(kf1, qfB, zz, 0, 0, 0);

        float pA0 = EXP2F(s0A[0]), pA1 = EXP2F(s0A[1]), pA2 = EXP2F(s0A[2]), pA3 = EXP2F(s0A[3]);
        float pA4 = EXP2F(s1A[0]), pA5 = EXP2F(s1A[1]), pA6 = EXP2F(s1A[2]), pA7 = EXP2F(s1A[3]);
        float pB0 = EXP2F(s0B[0]), pB1 = EXP2F(s0B[1]), pB2 = EXP2F(s0B[2]), pB3 = EXP2F(s0B[3]);
        float pB4 = EXP2F(s1B[0]), pB5 = EXP2F(s1B[1]), pB6 = EXP2F(s1B[2]), pB7 = EXP2F(s1B[3]);
        lsA += ((pA0 + pA1) + (pA2 + pA3)) + ((pA4 + pA5) + (pA6 + pA7));
        lsB += ((pB0 + pB1) + (pB2 + pB3)) + ((pB4 + pB5) + (pB6 + pB7));

        pk8 pfA, pfB;
        pfA.u[0] = cvt_pk_bf16(pA0, pA1); pfA.u[1] = cvt_pk_bf16(pA2, pA3);
        pfA.u[2] = cvt_pk_bf16(pA4, pA5); pfA.u[3] = cvt_pk_bf16(pA6, pA7);
        pfB.u[0] = cvt_pk_bf16(pB0, pB1); pfB.u[1] = cvt_pk_bf16(pB2, pB3);
        pfB.u[2] = cvt_pk_bf16(pB4, pB5); pfB.u[3] = cvt_pk_bf16(pB6, pB7);

        accA = __builtin_amdgcn_mfma_f32_16x16x32_bf16(cv, pfA.v, accA, 0, 0, 0);
        accB = __builtin_amdgcn_mfma_f32_16x16x32_bf16(cv, pfB.v, accB, 0, 0, 0);
    }

    lsA += __shfl_xor(lsA, 16, 64); lsA += __shfl_xor(lsA, 32, 64);
    lsB += __shfl_xor(lsB, 16, 64); lsB += __shfl_xor(lsB, 32, 64);

    __shared__ float red[8][2][64][5];
    red[kg][0][lane][0] = accA[0]; red[kg][0][lane][1] = accA[1];
    red[kg][0][lane][2] = accA[2]; red[kg][0][lane][3] = accA[3];
    red[kg][0][lane][4] = lsA;
    red[kg][1][lane][0] = accB[0]; red[kg][1][lane][1] = accB[1];
    red[kg][1][lane][2] = accB[2]; red[kg][1][lane][3] = accB[3];
    red[kg][1][lane][4] = lsB;
    __syncthreads();
    if (kg < 2) {
        int t = kg;
        float a0 = 0.f, a1 = 0.f, a2 = 0.f, a3 = 0.f, lt = 0.f;
#pragma unroll
        for (int g2 = 0; g2 < 8; ++g2) {
            a0 += red[g2][t][lane][0];
            a1 += red[g2][t][lane][1];
            a2 += red[g2][t][lane][2];
            a3 += red[g2][t][lane][3];
            lt += red[g2][t][lane][4];
        }
        float inv = 1.0f / lt;
        pk4 o;
        o.u[0] = cvt_pk_bf16(a0 * inv, a1 * inv);
        o.u[1] = cvt_pk_bf16(a2 * inv, a3 * inv);
        *reinterpret_cast<s4v*>(reinterpret_cast<short*>(attnob) +
            ((size_t)b * L_ + tp * 32 + t * 16 + lo) * 64 + h * 16 + 4 * hi) = o.v;
    }
}

// ---------------------------------------------------------------------------
// K5: o2 = LN( attnob @ w_fc + qc ; mha_ln, eps 1e-6 ), MFMA. grid 96 x 256.
// ---------------------------------------------------------------------------
__global__ __launch_bounds__(256) void gemm_fc_ln(
        const __hip_bfloat16* __restrict__ attnob, const float* __restrict__ qc,
        const float* __restrict__ wfc,
        const float* __restrict__ lnw, const float* __restrict__ lnb,
        float* __restrict__ o2) {
    const int rt = blockIdx.x * 4 + (threadIdx.x >> 6);   // 0..383
    const int lane = threadIdx.x & 63;
    const int lo = lane & 15, hi = lane >> 4;
    const f32x4 zz = {0.f, 0.f, 0.f, 0.f};

    s8v wf[4][2];
#pragma unroll
    for (int ct = 0; ct < 4; ++ct) {
        wf[ct][0] = wfrag_build(wfc, 64, ct, 0, lo, hi, 1.0f);
        wf[ct][1] = wfrag_build(wfc, 64, ct, 1, lo, hi, 1.0f);
    }
    const __hip_bfloat16* ar = attnob + (size_t)(rt * 16 + lo) * 64;
    s8v a0 = ldfrag_full(ar + 4 * hi, ar + 16 + 4 * hi);
    s8v a1 = ldfrag_full(ar + 32 + 4 * hi, ar + 48 + 4 * hi);

    f32x4 acc[4];
    const int row = rt * 16 + lo;
#pragma unroll
    for (int ct = 0; ct < 4; ++ct) {
        acc[ct] = zz;
        acc[ct] = __builtin_amdgcn_mfma_f32_16x16x32_bf16(wf[ct][0], a0, acc[ct], 0, 0, 0);
        acc[ct] = __builtin_amdgcn_mfma_f32_16x16x32_bf16(wf[ct][1], a1, acc[ct], 0, 0, 0);
        f32x4 rq = *reinterpret_cast<const f32x4*>(qc + (size_t)row * 64 + ct * 16 + 4 * hi);
        acc[ct][0] += rq[0]; acc[ct][1] += rq[1]; acc[ct][2] += rq[2]; acc[ct][3] += rq[3];
    }
    float s = 0.f;
#pragma unroll
    for (int ct = 0; ct < 4; ++ct) s += (acc[ct][0] + acc[ct][1]) + (acc[ct][2] + acc[ct][3]);
    s += __shfl_xor(s, 16, 64); s += __shfl_xor(s, 32, 64);
    float mean = s * (1.0f / 64.0f);
    float vs = 0.f;
#pragma unroll
    for (int ct = 0; ct < 4; ++ct) {
#pragma unroll
        for (int j = 0; j < 4; ++j) { float d = acc[ct][j] - mean; vs += d * d; }
    }
    vs += __shfl_xor(vs, 16, 64); vs += __shfl_xor(vs, 32, 64);
    float rsq = rsqrtf(vs * (1.0f / 64.0f) + 1e-6f);
#pragma unroll
    for (int ct = 0; ct < 4; ++ct) {
        f32x4 w4 = *reinterpret_cast<const f32x4*>(lnw + ct * 16 + 4 * hi);
        f32x4 b4 = *reinterpret_cast<const f32x4*>(lnb + ct * 16 + 4 * hi);
        f32x4 o;
#pragma unroll
        for (int j = 0; j < 4; ++j) o[j] = (acc[ct][j] - mean) * rsq * w4[j] + b4[j];
        *reinterpret_cast<f32x4*>(o2 + (size_t)row * 64 + ct * 16 + 4 * hi) = o;
    }
}

// ---------------------------------------------------------------------------
// K6 (FUSED pool + conv + lin_ln): per block = 16 output rows. grid 128 x 256.
// pool -> LDS xs; conv MFMA -> LDS x1s; lin MFMA (+bias+residual) -> LDS accs;
// cross-wave LN -> d_out.
// ---------------------------------------------------------------------------
__global__ __launch_bounds__(256) void tail_fused(
        const float* __restrict__ o2, const float* __restrict__ convw,
        const float* __restrict__ convb, const float* __restrict__ linw,
        const float* __restrict__ linb, const float* __restrict__ qx,
        const float* __restrict__ nw, const float* __restrict__ nb,
        float* __restrict__ out) {
    const int w = threadIdx.x >> 6;
    const int lane = threadIdx.x & 63;
    const int lo = lane & 15, hi = lane >> 4;
    const int rt = blockIdx.x;               // 0..127

    __shared__ short xs[16][68];
    __shared__ short x1s[16][136];
    __shared__ float accs[16][68];

    // W fragments (overlap the pool phase)
    s8v cwf[2][2];
#pragma unroll
    for (int c = 0; c < 2; ++c) {
        int ct = 2 * w + c;
        cwf[c][0] = wfrag_build(convw, 128, ct, 0, lo, hi, 1.0f);
        cwf[c][1] = wfrag_build(convw, 128, ct, 1, lo, hi, 1.0f);
    }
    s8v lwf[4];
#pragma unroll
    for (int ks = 0; ks < 4; ++ks)
        lwf[ks] = wfrag_build(linw, 64, w, ks, lo, hi, 1.0f);

    // ---- pool: x[rid][c] = mean of 3 consecutive o2 values ----
#pragma unroll
    for (int i = 0; i < 4; ++i) {
        int f = threadIdx.x + i * 256;       // 0..1023
        int r = f >> 6, c = f & 63;
        int rid = rt * 16 + r;
        int b = rid >> 10, ii = rid & 1023;
        const float* ob = o2 + (size_t)b * (L_ * 64) + 192 * ii + 3 * c;
        xs[r][c] = f2bf((ob[0] + ob[1] + ob[2]) * (1.0f / 3.0f));
    }
    __syncthreads();

    // ---- conv + relu -> x1s ----
    {
        const short* ar = &xs[lo][0];
        s8v a0 = ldsfrag(ar + 4 * hi, ar + 16 + 4 * hi);
        s8v a1 = ldsfrag(ar + 32 + 4 * hi, ar + 48 + 4 * hi);
        const f32x4 zz = {0.f, 0.f, 0.f, 0.f};
#pragma unroll
        for (int c = 0; c < 2; ++c) {
            int ct = 2 * w + c;
            f32x4 acc = zz;
            acc = __builtin_amdgcn_mfma_f32_16x16x32_bf16(cwf[c][0], a0, acc, 0, 0, 0);
            acc = __builtin_amdgcn_mfma_f32_16x16x32_bf16(cwf[c][1], a1, acc, 0, 0, 0);
            f32x4 bia = *reinterpret_cast<const f32x4*>(convb + ct * 16 + 4 * hi);
            pk4 o;
            o.u[0] = cvt_pk_bf16(fmaxf(acc[0] + bia[0], 0.f), fmaxf(acc[1] + bia[1], 0.f));
            o.u[1] = cvt_pk_bf16(fmaxf(acc[2] + bia[2], 0.f), fmaxf(acc[3] + bia[3], 0.f));
            *reinterpret_cast<s4v*>(&x1s[lo][ct * 16 + 4 * hi]) = o.v;
        }
    }
    __syncthreads();

    // ---- lin (+bias+residual) -> accs ----
    {
        const short* br = &x1s[lo][0];
        s8v af[4];
#pragma unroll
        for (int ks = 0; ks < 4; ++ks)
            af[ks] = ldsfrag(br + ks * 32 + 4 * hi, br + ks * 32 + 16 + 4 * hi);
        f32x4 acc = {0.f, 0.f, 0.f, 0.f};
#pragma unroll
        for (int ks = 0; ks < 4; ++ks)
            acc = __builtin_amdgcn_mfma_f32_16x16x32_bf16(lwf[ks], af[ks], acc, 0, 0, 0);
        int rid = rt * 16 + lo;
        f32x4 bia = *reinterpret_cast<const f32x4*>(linb + w * 16 + 4 * hi);
        f32x4 rq  = *reinterpret_cast<const f32x4*>(qx + (size_t)rid * 64 + w * 16 + 4 * hi);
#pragma unroll
        for (int j = 0; j < 4; ++j) accs[lo][w * 16 + 4 * hi + j] = acc[j] + bia[j] + rq[j];
    }
    __syncthreads();

    // ---- final LN (eps 1e-5) -> out ----
    {
        int r = 4 * w + hi;                  // row 0..15
        f32x4 v4 = *reinterpret_cast<const f32x4*>(&accs[r][lo * 4]);
        float sum = (v4[0] + v4[1]) + (v4[2] + v4[3]);
        sum += __shfl_xor(sum, 1, 64);
        sum += __shfl_xor(sum, 2, 64);
        sum += __shfl_xor(sum, 4, 64);
        sum += __shfl_xor(sum, 8, 64);
        float mean = sum * (1.0f / 64.0f);
        f32x4 d4;
        float vsum = 0.f;
#pragma unroll
        for (int j = 0; j < 4; ++j) { d4[j] = v4[j] - mean; vsum += d4[j] * d4[j]; }
        vsum += __shfl_xor(vsum, 1, 64);
        vsum += __shfl_xor(vsum, 2, 64);
        vsum += __shfl_xor(vsum, 4, 64);
        vsum += __shfl_xor(vsum, 8, 64);
        float rsq = rsqrtf(vsum * (1.0f / 64.0f) + 1e-5f);
        f32x4 w4 = *reinterpret_cast<const f32x4*>(nw + lo * 4);
        f32x4 b4 = *reinterpret_cast<const f32x4*>(nb + lo * 4);
        f32x4 o;
#pragma unroll
        for (int j = 0; j < 4; ++j) o[j] = d4[j] * rsq * w4[j] + b4[j];
        int rid = rt * 16 + r;
        *reinterpret_cast<f32x4*>(out + (size_t)rid * 64 + lo * 4) = o;
    }
}

// ---------------------------------------------------------------------------
extern "C" void kernel_launch(void* const* d_in, const int* in_sizes, int n_in,
                              void* d_out, int out_size, void* d_ws, size_t ws_size,
                              hipStream_t stream) {
    const float* q_x      = (const float*)d_in[0];
    const float* q_adj    = (const float*)d_in[1];
    const float* v_x      = (const float*)d_in[2];
    const float* v_adj    = (const float*)d_in[3];
    const float* w_qs     = (const float*)d_in[4];
    const float* w_ks     = (const float*)d_in[5];
    const float* w_vs     = (const float*)d_in[6];
    const float* w_fc     = (const float*)d_in[7];
    const float* mha_ln_w = (const float*)d_in[8];
    const float* mha_ln_b = (const float*)d_in[9];
    const float* conv_w   = (const float*)d_in[10];
    const float* conv_b   = (const float*)d_in[11];
    const float* lin_w    = (const float*)d_in[12];
    const float* lin_b    = (const float*)d_in[13];
    const float* norm_w   = (const float*)d_in[14];
    const float* norm_b   = (const float*)d_in[15];

    float* ws = (float*)d_ws;
    float* q1    = ws;                 // 131072 f each
    float* v1    = q1 + 131072;
    float* q2    = v1 + 131072;
    float* v2    = q2 + 131072;
    float* qc    = v2 + 131072;        // 393216 f
    float* o2    = qc + 393216;        // 393216 f
    __hip_bfloat16* qpk    = (__hip_bfloat16*)(o2 + 393216);   // [BH,96,64,8] packed
    __hip_bfloat16* kpk    = qpk + 393216;
    __hip_bfloat16* vpk    = kpk + 393216;
    __hip_bfloat16* attnob = vpk + 393216;                     // [B*L,64]
    __hip_bfloat16* xtq    = attnob + 393216;                  // [B,64,1024] bf16
    __hip_bfloat16* xtv    = xtq + 131072;
    __hip_bfloat16* q1t    = xtv + 131072;
    __hip_bfloat16* v1t    = q1t + 131072;
    float* out   = (float*)d_out;

    xpose<<<dim3(16, 4), 256, 0, stream>>>(q_x, v_x, xtq, xtv);
    spmm_mfma<<<dim3(64, 2, 2), 256, 0, stream>>>(q_adj, v_adj, xtq, xtv,
                                                  q1, v1, q1t, v1t, 1);
    spmm_mfma<<<dim3(64, 2, 2), 256, 0, stream>>>(q_adj, v_adj, q1t, v1t,
                                                  q2, v2, nullptr, nullptr, 0);
    gemm_qkv_ln<<<192, 256, 0, stream>>>(q_x, q1, q2, v_x, v1, v2,
                                         w_qs, w_ks, w_vs, qc, qpk, kpk, vpk);
    attn_mfma<<<768, 512, 0, stream>>>(qpk, kpk, vpk, attnob);
    gemm_fc_ln<<<96, 256, 0, stream>>>(attnob, qc, w_fc, mha_ln_w, mha_ln_b, o2);
    tail_fused<<<128, 256, 0, stream>>>(o2, conv_w, conv_b, lin_w, lin_b,
                                        q_x, norm_w, norm_b, out);
}